// Round 17
// baseline (493.719 us; speedup 1.0000x reference)
//
#include <hip/hip_runtime.h>
#include <math.h>

#define N_NODES 100000
#define N_EDGES 3200000
#define D_FEAT 256
#define GC_HID 20
#define DEC_HID 40
#define Z_DIM 32

#define EPB 2048          // edges per sort block
#define NBLK 1563         // ceil(3.2M / 2048)
#define SB 392            // node buckets of 256 (392*256 = 100352)
#define SBSH 8
#define S2CAP 12288       // per-bucket record cap

// ---------------- ws layout (bytes) ----------------
// h_pre  @ 0           8,000,000   (dead after 2nd gather; dbuf overlays @0)
// agg    @ 8,000,000   8,000,000   (dead after k_enc2)
// dbuf   @ 0          16,000,000   (k_decd output; overlays h_pre+agg)
// grec   @16,000,000  12,804,096   (bucket-sorted records; dead after 2nd gather)
// rec_r  @28,804,096  12,804,096   (dead after k_gscat)
//   pml (bf16 [N][64]) overlays rec_r after k_gscat: 12,804,096 bytes
// srow_r @41,608,192   1,228,518   (dead after k_gscat)
// pref_t @42,836,720   2,450,784   (dead after k_gscat)
//   zbuf overlays @41,608,192 after 2nd gather (12,800,000 -> end 54,408,192)
// row_ptr@45,287,504     400,004   (dead after 2nd gather)
// gtot   @45,687,508       1,568
// gbase  @45,689,076       1,572
// rs_s   @45,690,648     400,000   (dead after k_gc2)
// rec_s  @46,090,648   3,201,024   (dead after k_degs)
// srow_s @49,291,672   1,228,518   (dead after k_degs)   end = 50,520,190

__device__ inline unsigned short f2bf(float f) {
    unsigned u = __float_as_uint(f);
    return (unsigned short)((u + 0x7FFFu + ((u >> 16) & 1u)) >> 16);
}
__device__ inline float bf2f(unsigned short h) {
    return __uint_as_float((unsigned)h << 16);
}

// dual block-local counting sort (receiver u32 + sender u8 streams).
// ZERO global atomics (R13: each device-scope atomic = memory-side write).
__global__ __launch_bounds__(512) void k_sort(const int* __restrict__ snd,
                                              const int* __restrict__ rcv,
                                              unsigned* __restrict__ rec_r,
                                              unsigned char* __restrict__ rec_s,
                                              unsigned short* __restrict__ srow_r,
                                              unsigned short* __restrict__ srow_s) {
    __shared__ int es[EPB], er[EPB];
    __shared__ unsigned scan[SB + 1];
    __shared__ unsigned cur[SB];
    __shared__ unsigned sorted[EPB];
    __shared__ unsigned char sorteds[EPB];
    int b = blockIdx.x, t = threadIdx.x;
    int base = b * EPB;
    int cnt = min(EPB, N_EDGES - base);
    for (int i = t; i < cnt; i += 512) { es[i] = snd[base + i]; er[i] = rcv[base + i]; }

    for (int i = t; i < SB + 1; i += 512) scan[i] = 0u;
    __syncthreads();
    for (int i = t; i < cnt; i += 512) atomicAdd(&scan[(er[i] >> SBSH) + 1], 1u);
    __syncthreads();
    for (int off = 1; off < SB + 1; off <<= 1) {
        unsigned v = (t >= off && t < SB + 1) ? scan[t - off] : 0u;
        __syncthreads();
        if (t < SB + 1) scan[t] += v;
        __syncthreads();
    }
    for (int i = t; i < SB + 1; i += 512) srow_r[(size_t)b * (SB + 1) + i] = (unsigned short)scan[i];
    if (t < SB) cur[t] = scan[t];
    __syncthreads();
    for (int i = t; i < cnt; i += 512) {
        int r = er[i];
        unsigned pos = atomicAdd(&cur[r >> SBSH], 1u);
        sorted[pos] = ((unsigned)(r & 255) << 17) | (unsigned)es[i];
    }
    __syncthreads();
    for (int i = t; i < cnt; i += 512) rec_r[(size_t)base + i] = sorted[i];
    __syncthreads();

    for (int i = t; i < SB + 1; i += 512) scan[i] = 0u;
    __syncthreads();
    for (int i = t; i < cnt; i += 512) atomicAdd(&scan[(es[i] >> SBSH) + 1], 1u);
    __syncthreads();
    for (int off = 1; off < SB + 1; off <<= 1) {
        unsigned v = (t >= off && t < SB + 1) ? scan[t - off] : 0u;
        __syncthreads();
        if (t < SB + 1) scan[t] += v;
        __syncthreads();
    }
    for (int i = t; i < SB + 1; i += 512) srow_s[(size_t)b * (SB + 1) + i] = (unsigned short)scan[i];
    if (t < SB) cur[t] = scan[t];
    __syncthreads();
    for (int i = t; i < cnt; i += 512) {
        int s = es[i];
        unsigned pos = atomicAdd(&cur[s >> SBSH], 1u);
        sorteds[pos] = (unsigned char)(s & 255);
    }
    __syncthreads();
    for (int i = t; i < cnt; i += 512) rec_s[(size_t)base + i] = sorteds[i];
}

// sender-degree via per-bucket LDS histogram over sender-sorted runs
__global__ __launch_bounds__(512) void k_degs(const unsigned char* __restrict__ rec_s,
                                              const unsigned short* __restrict__ srow_s,
                                              float* __restrict__ rs_s) {
    __shared__ unsigned h[256];
    int s = blockIdx.x, t = threadIdx.x;
    if (t < 256) h[t] = 0u;
    __syncthreads();
    for (int k = t; k < NBLK; k += 512) {
        const unsigned short* row = srow_s + (size_t)k * (SB + 1);
        unsigned st = row[s], en = row[s + 1];
        const unsigned char* rp = rec_s + (size_t)k * EPB;
        for (unsigned i = st; i < en; ++i) atomicAdd(&h[rp[i]], 1u);
    }
    __syncthreads();
    if (t < 256) {
        int n = (s << SBSH) + t;
        if (n < N_NODES) rs_s[n] = rsqrtf(fmaxf((float)h[t], 1.0f));
    }
}

// per-bucket prefix over block segments: pref_t[s][k], totals gtot[s]
__global__ __launch_bounds__(256) void k_scanB(const unsigned short* __restrict__ srow_r,
                                               unsigned* __restrict__ pref_t,
                                               unsigned* __restrict__ gtot) {
    __shared__ unsigned buf[256];
    int s = blockIdx.x, t = threadIdx.x;
    unsigned run = 0;
    for (int k0 = 0; k0 < NBLK; k0 += 256) {
        int k = k0 + t;
        unsigned v = 0;
        if (k < NBLK) {
            const unsigned short* row = srow_r + (size_t)k * (SB + 1);
            v = (unsigned)row[s + 1] - (unsigned)row[s];
        }
        buf[t] = v;
        __syncthreads();
        for (int off = 1; off < 256; off <<= 1) {
            unsigned x = (t >= off) ? buf[t - off] : 0u;
            __syncthreads();
            buf[t] += x;
            __syncthreads();
        }
        if (k < NBLK) pref_t[(size_t)s * NBLK + k] = run + (buf[t] - v);
        unsigned tot = buf[255];
        __syncthreads();
        run += tot;
    }
    if (t == 0) gtot[s] = run;
}

// exclusive scan of bucket totals -> gbase[SB+1]
__global__ __launch_bounds__(512) void k_scanG(const unsigned* __restrict__ gtot,
                                               unsigned* __restrict__ gbase) {
    __shared__ unsigned buf[SB];
    int t = threadIdx.x;
    if (t < SB) buf[t] = gtot[t];
    __syncthreads();
    for (int off = 1; off < SB; off <<= 1) {
        unsigned x = (t >= off && t < SB) ? buf[t - off] : 0u;
        __syncthreads();
        if (t < SB) buf[t] += x;
        __syncthreads();
    }
    if (t < SB) gbase[t + 1] = buf[t];
    if (t == 0) gbase[0] = 0u;
}

// scatter block-sorted records to global bucket-sorted order
__global__ __launch_bounds__(256) void k_gscat(const unsigned* __restrict__ rec_r,
                                               const unsigned short* __restrict__ srow_r,
                                               const unsigned* __restrict__ pref_t,
                                               const unsigned* __restrict__ gbase,
                                               unsigned* __restrict__ grec) {
    __shared__ unsigned recs[EPB];
    __shared__ unsigned short srow[SB + 1];
    int b = blockIdx.x, t = threadIdx.x;
    int base = b * EPB;
    int cnt = min(EPB, N_EDGES - base);
    for (int i = t; i < cnt; i += 256) recs[i] = rec_r[(size_t)base + i];
    for (int i = t; i < SB + 1; i += 256) srow[i] = srow_r[(size_t)b * (SB + 1) + i];
    __syncthreads();
    for (int s = t; s < SB; s += 256) {
        unsigned lo = srow[s], hi = srow[s + 1];
        if (lo == hi) continue;
        unsigned dst = gbase[s] + pref_t[(size_t)s * NBLK + b];
        for (unsigned i = lo; i < hi; ++i) grec[dst + (i - lo)] = recs[i];
    }
}

// within-bucket counting sort by local receiver (in-place) + CSR row_ptr
__global__ __launch_bounds__(256) void k_sort2(unsigned* __restrict__ grec,
                                               const unsigned* __restrict__ gbase,
                                               unsigned* __restrict__ row_ptr) {
    __shared__ unsigned recs[S2CAP];     // 48 KB
    __shared__ unsigned hist[256];
    __shared__ unsigned scan[256];
    __shared__ unsigned cur[256];
    int s = blockIdx.x, t = threadIdx.x;
    unsigned lo = gbase[s], hi = gbase[s + 1];
    unsigned cnt = min(hi - lo, (unsigned)S2CAP);
    for (unsigned i = t; i < cnt; i += 256) recs[i] = grec[lo + i];
    hist[t] = 0u;
    __syncthreads();
    for (unsigned i = t; i < cnt; i += 256) atomicAdd(&hist[recs[i] >> 17], 1u);
    __syncthreads();
    unsigned v = hist[t];
    scan[t] = v;
    __syncthreads();
    for (int off = 1; off < 256; off <<= 1) {
        unsigned x = (t >= off) ? scan[t - off] : 0u;
        __syncthreads();
        scan[t] += x;
        __syncthreads();
    }
    unsigned excl = scan[t] - v;
    {
        int n = (s << SBSH) + t;
        if (n <= N_NODES) row_ptr[n] = lo + excl;
    }
    cur[t] = excl;
    __syncthreads();
    for (unsigned i = t; i < cnt; i += 256) {
        unsigned rec = recs[i];
        unsigned pos = atomicAdd(&cur[rec >> 17], 1u);
        grec[lo + pos] = rec & 0x1FFFFu;
    }
}

// pure CSR gather: 5 lanes per node, one float4 each; zero atomics.
__global__ __launch_bounds__(320) void k_gather(const unsigned* __restrict__ row_ptr,
                                                const unsigned* __restrict__ grec,
                                                const float* __restrict__ src,
                                                float* __restrict__ dst) {
    int gid = blockIdx.x * 320 + threadIdx.x;
    int node = gid / 5, q = gid % 5;
    if (node >= N_NODES) return;
    unsigned lo = row_ptr[node], hi = row_ptr[node + 1];
    float4 a0 = make_float4(0.f, 0.f, 0.f, 0.f);
    float4 a1 = make_float4(0.f, 0.f, 0.f, 0.f);
    float4 a2 = make_float4(0.f, 0.f, 0.f, 0.f);
    float4 a3 = make_float4(0.f, 0.f, 0.f, 0.f);
    unsigned e = lo;
    for (; e + 4 <= hi; e += 4) {
        unsigned s0 = grec[e], s1 = grec[e + 1], s2 = grec[e + 2], s3 = grec[e + 3];
        float4 v0 = ((const float4*)src)[s0 * 5 + q];
        float4 v1 = ((const float4*)src)[s1 * 5 + q];
        float4 v2 = ((const float4*)src)[s2 * 5 + q];
        float4 v3 = ((const float4*)src)[s3 * 5 + q];
        a0.x += v0.x; a0.y += v0.y; a0.z += v0.z; a0.w += v0.w;
        a1.x += v1.x; a1.y += v1.y; a1.z += v1.z; a1.w += v1.w;
        a2.x += v2.x; a2.y += v2.y; a2.z += v2.z; a2.w += v2.w;
        a3.x += v3.x; a3.y += v3.y; a3.z += v3.z; a3.w += v3.w;
    }
    for (; e < hi; ++e) {
        unsigned s0 = grec[e];
        float4 v0 = ((const float4*)src)[s0 * 5 + q];
        a0.x += v0.x; a0.y += v0.y; a0.z += v0.z; a0.w += v0.w;
    }
    a0.x += a1.x + a2.x + a3.x;
    a0.y += a1.y + a2.y + a3.y;
    a0.z += a1.z + a2.z + a3.z;
    a0.w += a1.w + a2.w + a3.w;
    float sc = rsqrtf(fmaxf((float)(hi - lo), 1.0f));
    a0.x *= sc; a0.y *= sc; a0.z *= sc; a0.w *= sc;
    ((float4*)dst)[node * 5 + q] = a0;
}

// FUSED gc1 + encoder-partials: nodes read ONCE. 1563 blocks x 576 thr
// (9 waves). Per 16-K chunk, one 64x17 LDS tile; wave0 runs gc1
// (20 accs + softmax -> h_pre); waves 1..8 compute the nodes-part of
// mu/ls (octet og = wave-1, 8 accs, W rows 20..276) -> pml bf16.
__global__ __launch_bounds__(576) void k_gc1f(const float* __restrict__ nodes,
                                              const float* __restrict__ W1,
                                              const float* __restrict__ b1,
                                              const float* __restrict__ Wmu,
                                              const float* __restrict__ Wls,
                                              const float* __restrict__ rs_s,
                                              float* __restrict__ h_pre,
                                              unsigned short* __restrict__ pml) {
    __shared__ float tile[64 * 17];    // 4,352 B
    int t = threadIdx.x;
    int wave = __builtin_amdgcn_readfirstlane(t >> 6);  // 0..8, scalarized
    int lane = t & 63;
    int n0 = blockIdx.x * 64;
    int node = n0 + lane;

    int og = wave - 1;                  // valid for waves 1..8
    int half = og >> 2;
    int co = (og & 3) << 3;
    const float* W = half ? Wls : Wmu;  // unused by wave0

    float accA[GC_HID];                 // wave0 only
    float accB[8];                      // octet waves only
    if (wave == 0) {
#pragma unroll
        for (int j = 0; j < GC_HID; ++j) accA[j] = b1[j];
    } else {
#pragma unroll
        for (int j = 0; j < 8; ++j) accB[j] = 0.0f;
    }

    int r = t >> 2, k4 = t & 3;
    for (int ch = 0; ch < 16; ++ch) {
        __syncthreads();
        if (t < 256) {
            int gn = n0 + r;
            float4 v = (gn < N_NODES)
                ? ((const float4*)nodes)[(size_t)gn * 64 + ch * 4 + k4]
                : make_float4(0.f, 0.f, 0.f, 0.f);
            float* dst = &tile[r * 17 + k4 * 4];
            dst[0] = v.x; dst[1] = v.y; dst[2] = v.z; dst[3] = v.w;
        }
        __syncthreads();
        if (wave == 0) {
            const float* wb = W1 + ch * 16 * GC_HID;
#pragma unroll
            for (int kk = 0; kk < 16; ++kk) {
                float x = tile[lane * 17 + kk];
                const float* wr = wb + kk * GC_HID;
#pragma unroll
                for (int j = 0; j < GC_HID; ++j) accA[j] = fmaf(x, wr[j], accA[j]);
            }
        } else {
#pragma unroll
            for (int kk = 0; kk < 16; ++kk) {
                float x = tile[lane * 17 + kk];
                const float* wr = W + (GC_HID + ch * 16 + kk) * Z_DIM + co;
#pragma unroll
                for (int j = 0; j < 8; ++j) accB[j] = fmaf(x, wr[j], accB[j]);
            }
        }
    }
    if (node >= N_NODES) return;
    if (wave == 0) {
        float mx = -1e30f;
#pragma unroll
        for (int j = 0; j < GC_HID; ++j) {
            accA[j] = fmaxf(accA[j], 0.0f);
            mx = fmaxf(mx, accA[j]);
        }
        float s = 0.0f;
#pragma unroll
        for (int j = 0; j < GC_HID; ++j) {
            accA[j] = __expf(accA[j] - mx);
            s += accA[j];
        }
        float inv = rs_s[node] / s;
#pragma unroll
        for (int j = 0; j < GC_HID; ++j) accA[j] *= inv;
        float4* o = (float4*)&h_pre[(size_t)node * GC_HID];
        o[0] = make_float4(accA[0],  accA[1],  accA[2],  accA[3]);
        o[1] = make_float4(accA[4],  accA[5],  accA[6],  accA[7]);
        o[2] = make_float4(accA[8],  accA[9],  accA[10], accA[11]);
        o[3] = make_float4(accA[12], accA[13], accA[14], accA[15]);
        o[4] = make_float4(accA[16], accA[17], accA[18], accA[19]);
    } else {
        uint4 p;
        p.x = (unsigned)f2bf(accB[0]) | ((unsigned)f2bf(accB[1]) << 16);
        p.y = (unsigned)f2bf(accB[2]) | ((unsigned)f2bf(accB[3]) << 16);
        p.z = (unsigned)f2bf(accB[4]) | ((unsigned)f2bf(accB[5]) << 16);
        p.w = (unsigned)f2bf(accB[6]) | ((unsigned)f2bf(accB[7]) << 16);
        *(uint4*)(pml + (size_t)node * 64 + half * 32 + co) = p;
    }
}

// GC layer 2 transform: h2_pre = softmax(relu(h1@W2+b2)) * rs_s
__global__ __launch_bounds__(256) void k_gc2(const float* __restrict__ h1in,
                                             const float* __restrict__ W2,
                                             const float* __restrict__ b2,
                                             const float* __restrict__ rs_s,
                                             float* __restrict__ h2_pre) {
    __shared__ float Wsh[GC_HID * GC_HID];
    __shared__ float bsh[GC_HID];
    int tid = threadIdx.x;
    if (tid < GC_HID * GC_HID) Wsh[tid] = W2[tid];
    if (tid < GC_HID) bsh[tid] = b2[tid];
    __syncthreads();
    int node = blockIdx.x * 256 + tid;
    if (node >= N_NODES) return;
    const float4* ap = (const float4*)&h1in[node * GC_HID];
    float4 a0 = ap[0], a1 = ap[1], a2 = ap[2], a3 = ap[3], a4 = ap[4];
    float h1[GC_HID] = {a0.x,a0.y,a0.z,a0.w, a1.x,a1.y,a1.z,a1.w,
                        a2.x,a2.y,a2.z,a2.w, a3.x,a3.y,a3.z,a3.w,
                        a4.x,a4.y,a4.z,a4.w};
    float t[GC_HID];
#pragma unroll
    for (int j = 0; j < GC_HID; ++j) t[j] = bsh[j];
#pragma unroll
    for (int i = 0; i < GC_HID; ++i) {
        float x = h1[i];
#pragma unroll
        for (int j = 0; j < GC_HID; ++j) t[j] = fmaf(x, Wsh[i * GC_HID + j], t[j]);
    }
    float mx = -1e30f;
#pragma unroll
    for (int j = 0; j < GC_HID; ++j) { t[j] = fmaxf(t[j], 0.0f); mx = fmaxf(mx, t[j]); }
    float s = 0.0f;
#pragma unroll
    for (int j = 0; j < GC_HID; ++j) { t[j] = __expf(t[j] - mx); s += t[j]; }
    float inv = rs_s[node] / s;
#pragma unroll
    for (int j = 0; j < GC_HID; ++j) t[j] *= inv;
    float4* o = (float4*)&h2_pre[node * GC_HID];
    o[0] = make_float4(t[0],  t[1],  t[2],  t[3]);
    o[1] = make_float4(t[4],  t[5],  t[6],  t[7]);
    o[2] = make_float4(t[8],  t[9],  t[10], t[11]);
    o[3] = make_float4(t[12], t[13], t[14], t[15]);
    o[4] = make_float4(t[16], t[17], t[18], t[19]);
}

// encoder finish: mu/ls = bias + pml + h2 @ W[0:20]. Octet split,
// grid (1563, 2), block 256 = 4 waves x 64 nodes.
__global__ __launch_bounds__(256) void k_enc2(const float* __restrict__ h2in,
                                              const unsigned short* __restrict__ pml,
                                              const float* __restrict__ Wmu,
                                              const float* __restrict__ bmu,
                                              const float* __restrict__ Wls,
                                              const float* __restrict__ bls,
                                              float* __restrict__ mu_out,
                                              float* __restrict__ ls_out) {
    int t = threadIdx.x;
    int wave = t >> 6, lane = t & 63;
    int og = __builtin_amdgcn_readfirstlane(wave | ((int)blockIdx.y << 2)); // 0..7
    int half = og >> 2;
    int co = (og & 3) << 3;
    int node = blockIdx.x * 64 + lane;
    if (node >= N_NODES) return;
    const float* W  = half ? Wls : Wmu;
    const float* bb = half ? bls : bmu;
    float* out      = half ? ls_out : mu_out;

    uint4 p = *(const uint4*)(pml + (size_t)node * 64 + half * 32 + co);
    float acc[8];
    acc[0] = bf2f((unsigned short)(p.x & 0xFFFFu));
    acc[1] = bf2f((unsigned short)(p.x >> 16));
    acc[2] = bf2f((unsigned short)(p.y & 0xFFFFu));
    acc[3] = bf2f((unsigned short)(p.y >> 16));
    acc[4] = bf2f((unsigned short)(p.z & 0xFFFFu));
    acc[5] = bf2f((unsigned short)(p.z >> 16));
    acc[6] = bf2f((unsigned short)(p.w & 0xFFFFu));
    acc[7] = bf2f((unsigned short)(p.w >> 16));
#pragma unroll
    for (int j = 0; j < 8; ++j) acc[j] += bb[co + j];

    const float4* hp = (const float4*)(h2in + (size_t)node * GC_HID);
#pragma unroll
    for (int v = 0; v < 5; ++v) {
        float4 hh = hp[v];
#pragma unroll
        for (int c = 0; c < 4; ++c) {
            float x = (c == 0) ? hh.x : (c == 1) ? hh.y : (c == 2) ? hh.z : hh.w;
            const float* wr = W + (v * 4 + c) * Z_DIM + co;
#pragma unroll
            for (int j = 0; j < 8; ++j) acc[j] = fmaf(x, wr[j], acc[j]);
        }
    }
    float4* op = (float4*)(out + (size_t)node * Z_DIM + co);
    op[0] = make_float4(acc[0], acc[1], acc[2], acc[3]);
    op[1] = make_float4(acc[4], acc[5], acc[6], acc[7]);
}

// reparameterization: z = mu + (1e-4 + exp(0.5*ls)) * eps
__global__ __launch_bounds__(256) void k_z(const float* __restrict__ mu,
                                           const float* __restrict__ ls,
                                           const float* __restrict__ eps,
                                           float* __restrict__ z) {
    int i = blockIdx.x * 256 + threadIdx.x;
    if (i >= N_NODES * Z_DIM / 4) return;
    float4 m = ((const float4*)mu)[i];
    float4 l = ((const float4*)ls)[i];
    float4 e = ((const float4*)eps)[i];
    float4 zz;
    zz.x = m.x + (1e-4f + __expf(0.5f * l.x)) * e.x;
    zz.y = m.y + (1e-4f + __expf(0.5f * l.y)) * e.y;
    zz.z = m.z + (1e-4f + __expf(0.5f * l.z)) * e.z;
    zz.w = m.w + (1e-4f + __expf(0.5f * l.w)) * e.w;
    ((float4*)z)[i] = zz;
}

// decoder stage 1: d = relu(z@Wd1+bd1), thread per node (weights uniform)
__global__ __launch_bounds__(256) void k_decd(const float* __restrict__ z,
                                              const float* __restrict__ Wd1,
                                              const float* __restrict__ bd1,
                                              float* __restrict__ dbuf) {
    int node = blockIdx.x * 256 + threadIdx.x;
    if (node >= N_NODES) return;
    float d[DEC_HID];
#pragma unroll
    for (int j = 0; j < DEC_HID; ++j) d[j] = bd1[j];
    const float4* zp = (const float4*)(z + (size_t)node * Z_DIM);
#pragma unroll
    for (int v = 0; v < Z_DIM / 4; ++v) {
        float4 zz = zp[v];
#pragma unroll
        for (int c = 0; c < 4; ++c) {
            float x = (c == 0) ? zz.x : (c == 1) ? zz.y : (c == 2) ? zz.z : zz.w;
            const float* wr = Wd1 + (v * 4 + c) * DEC_HID;
#pragma unroll
            for (int j = 0; j < DEC_HID; ++j) d[j] = fmaf(x, wr[j], d[j]);
        }
    }
    float4* op = (float4*)(dbuf + (size_t)node * DEC_HID);
#pragma unroll
    for (int v = 0; v < DEC_HID / 4; ++v)
        op[v] = make_float4(fmaxf(d[4*v], 0.f), fmaxf(d[4*v+1], 0.f),
                            fmaxf(d[4*v+2], 0.f), fmaxf(d[4*v+3], 0.f));
}

// decoder stage 2: chunk id forced wave-uniform via readfirstlane; lane = node.
__global__ __launch_bounds__(256) void k_decx(const float* __restrict__ dbuf,
                                              const float* __restrict__ Wd2,
                                              const float* __restrict__ bd2,
                                              float* __restrict__ X) {
    int lane = threadIdx.x & 63;
    int wv   = threadIdx.x >> 6;             // 0..3
    int ch   = __builtin_amdgcn_readfirstlane(((blockIdx.x & 1) << 2) | wv);
    int node = (blockIdx.x >> 1) * 64 + lane;
    if (node >= N_NODES) return;
    int co = ch << 5;
    float o[32];
#pragma unroll
    for (int j = 0; j < 32; ++j) o[j] = bd2[co + j];
    const float4* dp = (const float4*)(dbuf + (size_t)node * DEC_HID);
#pragma unroll
    for (int v = 0; v < DEC_HID / 4; ++v) {
        float4 dd = dp[v];
#pragma unroll
        for (int c = 0; c < 4; ++c) {
            float x = (c == 0) ? dd.x : (c == 1) ? dd.y : (c == 2) ? dd.z : dd.w;
            const float* wr = Wd2 + (v * 4 + c) * D_FEAT + co;
#pragma unroll
            for (int j = 0; j < 32; ++j) o[j] = fmaf(x, wr[j], o[j]);
        }
    }
    float4* xp = (float4*)(X + (size_t)node * D_FEAT + co);
#pragma unroll
    for (int v = 0; v < 8; ++v)
        xp[v] = make_float4(o[4*v], o[4*v+1], o[4*v+2], o[4*v+3]);
}

extern "C" void kernel_launch(void* const* d_in, const int* in_sizes, int n_in,
                              void* d_out, int out_size, void* d_ws, size_t ws_size,
                              hipStream_t stream) {
    const float* nodes = (const float*)d_in[0];
    const int*   snd   = (const int*)d_in[1];
    const int*   rcv   = (const int*)d_in[2];
    const float* eps   = (const float*)d_in[3];
    const float* W1    = (const float*)d_in[4];
    const float* b1    = (const float*)d_in[5];
    const float* W2    = (const float*)d_in[6];
    const float* b2    = (const float*)d_in[7];
    const float* Wmu   = (const float*)d_in[8];
    const float* bmu   = (const float*)d_in[9];
    const float* Wls   = (const float*)d_in[10];
    const float* bls   = (const float*)d_in[11];
    const float* Wd1   = (const float*)d_in[12];
    const float* bd1   = (const float*)d_in[13];
    const float* Wd2   = (const float*)d_in[14];
    const float* bd2   = (const float*)d_in[15];

    char* ws = (char*)d_ws;
    float*          h_pre    = (float*)(ws);
    float*          agg      = (float*)(ws + 8000000);
    float*          dbuf     = (float*)(ws);              // overlays h_pre+agg (dead)
    unsigned*       grec     = (unsigned*)(ws + 16000000);
    unsigned*       rec_r    = (unsigned*)(ws + 28804096);
    unsigned short* pml      = (unsigned short*)(ws + 28804096); // overlays rec_r post-gscat
    unsigned short* srow_r   = (unsigned short*)(ws + 41608192);
    unsigned*       pref_t   = (unsigned*)(ws + 42836720);
    float*          zbuf     = (float*)(ws + 41608192);   // overlays srow_r/pref_t/row_ptr post-gather
    unsigned*       row_ptr  = (unsigned*)(ws + 45287504);
    unsigned*       gtot     = (unsigned*)(ws + 45687508);
    unsigned*       gbase    = (unsigned*)(ws + 45689076);
    float*          rs_s     = (float*)(ws + 45690648);
    unsigned char*  rec_s    = (unsigned char*)(ws + 46090648);
    unsigned short* srow_s   = (unsigned short*)(ws + 49291672);

    float* X      = (float*)d_out;
    float* mu_out = X + (size_t)N_NODES * D_FEAT;
    float* ls_out = mu_out + (size_t)N_NODES * Z_DIM;

    k_sort<<<NBLK, 512, 0, stream>>>(snd, rcv, rec_r, rec_s, srow_r, srow_s);
    k_degs<<<SB, 512, 0, stream>>>(rec_s, srow_s, rs_s);
    k_scanB<<<SB, 256, 0, stream>>>(srow_r, pref_t, gtot);
    k_scanG<<<1, 512, 0, stream>>>(gtot, gbase);
    k_gscat<<<NBLK, 256, 0, stream>>>(rec_r, srow_r, pref_t, gbase, grec);
    k_sort2<<<SB, 256, 0, stream>>>(grec, gbase, row_ptr);

    // fused gc1 + encoder nodes-partials (nodes read once)
    k_gc1f<<<1563, 576, 0, stream>>>(nodes, W1, b1, Wmu, Wls, rs_s, h_pre, pml);
    k_gather<<<1563, 320, 0, stream>>>(row_ptr, grec, h_pre, agg);
    k_gc2<<<391, 256, 0, stream>>>(agg, W2, b2, rs_s, h_pre);
    k_gather<<<1563, 320, 0, stream>>>(row_ptr, grec, h_pre, agg);

    k_enc2<<<dim3(1563, 2), 256, 0, stream>>>(agg, pml, Wmu, bmu, Wls, bls,
                                              mu_out, ls_out);
    k_z<<<3125, 256, 0, stream>>>(mu_out, ls_out, eps, zbuf);
    k_decd<<<391, 256, 0, stream>>>(zbuf, Wd1, bd1, dbuf);
    k_decx<<<3126, 256, 0, stream>>>(dbuf, Wd2, bd2, X);
}

// Round 18
// 492.200 us; speedup vs baseline: 1.0031x; 1.0031x over previous
//
#include <hip/hip_runtime.h>
#include <math.h>

#define N_NODES 100000
#define N_EDGES 3200000
#define D_FEAT 256
#define GC_HID 20
#define DEC_HID 40
#define Z_DIM 32

#define EPB 2048          // edges per sort block
#define NBLK 1563         // ceil(3.2M / 2048)
#define SB 392            // node buckets of 256 (392*256 = 100352)
#define SBSH 8
#define S2CAP 12288       // per-bucket record cap

// ---------------- ws layout (bytes) ----------------
// h_pre  @ 0           8,000,000   (dead after 2nd gather; dbuf overlays @0)
// agg    @ 8,000,000   8,000,000   (dead after k_enc2)
// dbuf   @ 0          16,000,000   (k_decd output; overlays h_pre+agg)
// grec   @16,000,000  12,804,096   (bucket-sorted records; dead after 2nd gather)
// rec_r  @28,804,096  12,804,096   (dead after k_gscat)
//   pml (bf16 [N][64]) overlays rec_r after k_gscat
// srow_r @41,608,192   1,228,518   (dead after k_gscat)
// pref_t @42,836,720   2,450,784   (dead after k_gscat)
//   zbuf overlays @41,608,192 after 2nd gather
// row_ptr@45,287,504     400,004
// gtot   @45,687,508       1,568
// gbase  @45,689,076       1,572
// rs_s   @45,690,648     400,000
// rec_s  @46,090,648   3,201,024
// srow_s @49,291,672   1,228,518   end = 50,520,190

__device__ inline unsigned short f2bf(float f) {
    unsigned u = __float_as_uint(f);
    return (unsigned short)((u + 0x7FFFu + ((u >> 16) & 1u)) >> 16);
}
__device__ inline float bf2f(unsigned short h) {
    return __uint_as_float((unsigned)h << 16);
}

// dual block-local counting sort (receiver u32 + sender u8 streams).
// ZERO global atomics (R13: each device-scope atomic = memory-side write).
__global__ __launch_bounds__(512) void k_sort(const int* __restrict__ snd,
                                              const int* __restrict__ rcv,
                                              unsigned* __restrict__ rec_r,
                                              unsigned char* __restrict__ rec_s,
                                              unsigned short* __restrict__ srow_r,
                                              unsigned short* __restrict__ srow_s) {
    __shared__ int es[EPB], er[EPB];
    __shared__ unsigned scan[SB + 1];
    __shared__ unsigned cur[SB];
    __shared__ unsigned sorted[EPB];
    __shared__ unsigned char sorteds[EPB];
    int b = blockIdx.x, t = threadIdx.x;
    int base = b * EPB;
    int cnt = min(EPB, N_EDGES - base);
    for (int i = t; i < cnt; i += 512) { es[i] = snd[base + i]; er[i] = rcv[base + i]; }

    for (int i = t; i < SB + 1; i += 512) scan[i] = 0u;
    __syncthreads();
    for (int i = t; i < cnt; i += 512) atomicAdd(&scan[(er[i] >> SBSH) + 1], 1u);
    __syncthreads();
    for (int off = 1; off < SB + 1; off <<= 1) {
        unsigned v = (t >= off && t < SB + 1) ? scan[t - off] : 0u;
        __syncthreads();
        if (t < SB + 1) scan[t] += v;
        __syncthreads();
    }
    for (int i = t; i < SB + 1; i += 512) srow_r[(size_t)b * (SB + 1) + i] = (unsigned short)scan[i];
    if (t < SB) cur[t] = scan[t];
    __syncthreads();
    for (int i = t; i < cnt; i += 512) {
        int r = er[i];
        unsigned pos = atomicAdd(&cur[r >> SBSH], 1u);
        sorted[pos] = ((unsigned)(r & 255) << 17) | (unsigned)es[i];
    }
    __syncthreads();
    for (int i = t; i < cnt; i += 512) rec_r[(size_t)base + i] = sorted[i];
    __syncthreads();

    for (int i = t; i < SB + 1; i += 512) scan[i] = 0u;
    __syncthreads();
    for (int i = t; i < cnt; i += 512) atomicAdd(&scan[(es[i] >> SBSH) + 1], 1u);
    __syncthreads();
    for (int off = 1; off < SB + 1; off <<= 1) {
        unsigned v = (t >= off && t < SB + 1) ? scan[t - off] : 0u;
        __syncthreads();
        if (t < SB + 1) scan[t] += v;
        __syncthreads();
    }
    for (int i = t; i < SB + 1; i += 512) srow_s[(size_t)b * (SB + 1) + i] = (unsigned short)scan[i];
    if (t < SB) cur[t] = scan[t];
    __syncthreads();
    for (int i = t; i < cnt; i += 512) {
        int s = es[i];
        unsigned pos = atomicAdd(&cur[s >> SBSH], 1u);
        sorteds[pos] = (unsigned char)(s & 255);
    }
    __syncthreads();
    for (int i = t; i < cnt; i += 512) rec_s[(size_t)base + i] = sorteds[i];
}

// sender-degree via per-bucket LDS histogram over sender-sorted runs
__global__ __launch_bounds__(512) void k_degs(const unsigned char* __restrict__ rec_s,
                                              const unsigned short* __restrict__ srow_s,
                                              float* __restrict__ rs_s) {
    __shared__ unsigned h[256];
    int s = blockIdx.x, t = threadIdx.x;
    if (t < 256) h[t] = 0u;
    __syncthreads();
    for (int k = t; k < NBLK; k += 512) {
        const unsigned short* row = srow_s + (size_t)k * (SB + 1);
        unsigned st = row[s], en = row[s + 1];
        const unsigned char* rp = rec_s + (size_t)k * EPB;
        for (unsigned i = st; i < en; ++i) atomicAdd(&h[rp[i]], 1u);
    }
    __syncthreads();
    if (t < 256) {
        int n = (s << SBSH) + t;
        if (n < N_NODES) rs_s[n] = rsqrtf(fmaxf((float)h[t], 1.0f));
    }
}

// per-bucket prefix over block segments: pref_t[s][k], totals gtot[s]
__global__ __launch_bounds__(256) void k_scanB(const unsigned short* __restrict__ srow_r,
                                               unsigned* __restrict__ pref_t,
                                               unsigned* __restrict__ gtot) {
    __shared__ unsigned buf[256];
    int s = blockIdx.x, t = threadIdx.x;
    unsigned run = 0;
    for (int k0 = 0; k0 < NBLK; k0 += 256) {
        int k = k0 + t;
        unsigned v = 0;
        if (k < NBLK) {
            const unsigned short* row = srow_r + (size_t)k * (SB + 1);
            v = (unsigned)row[s + 1] - (unsigned)row[s];
        }
        buf[t] = v;
        __syncthreads();
        for (int off = 1; off < 256; off <<= 1) {
            unsigned x = (t >= off) ? buf[t - off] : 0u;
            __syncthreads();
            buf[t] += x;
            __syncthreads();
        }
        if (k < NBLK) pref_t[(size_t)s * NBLK + k] = run + (buf[t] - v);
        unsigned tot = buf[255];
        __syncthreads();
        run += tot;
    }
    if (t == 0) gtot[s] = run;
}

// exclusive scan of bucket totals -> gbase[SB+1]
__global__ __launch_bounds__(512) void k_scanG(const unsigned* __restrict__ gtot,
                                               unsigned* __restrict__ gbase) {
    __shared__ unsigned buf[SB];
    int t = threadIdx.x;
    if (t < SB) buf[t] = gtot[t];
    __syncthreads();
    for (int off = 1; off < SB; off <<= 1) {
        unsigned x = (t >= off && t < SB) ? buf[t - off] : 0u;
        __syncthreads();
        if (t < SB) buf[t] += x;
        __syncthreads();
    }
    if (t < SB) gbase[t + 1] = buf[t];
    if (t == 0) gbase[0] = 0u;
}

// scatter block-sorted records to global bucket-sorted order
__global__ __launch_bounds__(256) void k_gscat(const unsigned* __restrict__ rec_r,
                                               const unsigned short* __restrict__ srow_r,
                                               const unsigned* __restrict__ pref_t,
                                               const unsigned* __restrict__ gbase,
                                               unsigned* __restrict__ grec) {
    __shared__ unsigned recs[EPB];
    __shared__ unsigned short srow[SB + 1];
    int b = blockIdx.x, t = threadIdx.x;
    int base = b * EPB;
    int cnt = min(EPB, N_EDGES - base);
    for (int i = t; i < cnt; i += 256) recs[i] = rec_r[(size_t)base + i];
    for (int i = t; i < SB + 1; i += 256) srow[i] = srow_r[(size_t)b * (SB + 1) + i];
    __syncthreads();
    for (int s = t; s < SB; s += 256) {
        unsigned lo = srow[s], hi = srow[s + 1];
        if (lo == hi) continue;
        unsigned dst = gbase[s] + pref_t[(size_t)s * NBLK + b];
        for (unsigned i = lo; i < hi; ++i) grec[dst + (i - lo)] = recs[i];
    }
}

// within-bucket counting sort by local receiver (in-place) + CSR row_ptr
__global__ __launch_bounds__(256) void k_sort2(unsigned* __restrict__ grec,
                                               const unsigned* __restrict__ gbase,
                                               unsigned* __restrict__ row_ptr) {
    __shared__ unsigned recs[S2CAP];     // 48 KB
    __shared__ unsigned hist[256];
    __shared__ unsigned scan[256];
    __shared__ unsigned cur[256];
    int s = blockIdx.x, t = threadIdx.x;
    unsigned lo = gbase[s], hi = gbase[s + 1];
    unsigned cnt = min(hi - lo, (unsigned)S2CAP);
    for (unsigned i = t; i < cnt; i += 256) recs[i] = grec[lo + i];
    hist[t] = 0u;
    __syncthreads();
    for (unsigned i = t; i < cnt; i += 256) atomicAdd(&hist[recs[i] >> 17], 1u);
    __syncthreads();
    unsigned v = hist[t];
    scan[t] = v;
    __syncthreads();
    for (int off = 1; off < 256; off <<= 1) {
        unsigned x = (t >= off) ? scan[t - off] : 0u;
        __syncthreads();
        scan[t] += x;
        __syncthreads();
    }
    unsigned excl = scan[t] - v;
    {
        int n = (s << SBSH) + t;
        if (n <= N_NODES) row_ptr[n] = lo + excl;
    }
    cur[t] = excl;
    __syncthreads();
    for (unsigned i = t; i < cnt; i += 256) {
        unsigned rec = recs[i];
        unsigned pos = atomicAdd(&cur[rec >> 17], 1u);
        grec[lo + pos] = rec & 0x1FFFFu;
    }
}

// pure CSR gather: 5 lanes per node, one float4 each; zero atomics.
__global__ __launch_bounds__(320) void k_gather(const unsigned* __restrict__ row_ptr,
                                                const unsigned* __restrict__ grec,
                                                const float* __restrict__ src,
                                                float* __restrict__ dst) {
    int gid = blockIdx.x * 320 + threadIdx.x;
    int node = gid / 5, q = gid % 5;
    if (node >= N_NODES) return;
    unsigned lo = row_ptr[node], hi = row_ptr[node + 1];
    float4 a0 = make_float4(0.f, 0.f, 0.f, 0.f);
    float4 a1 = make_float4(0.f, 0.f, 0.f, 0.f);
    float4 a2 = make_float4(0.f, 0.f, 0.f, 0.f);
    float4 a3 = make_float4(0.f, 0.f, 0.f, 0.f);
    unsigned e = lo;
    for (; e + 4 <= hi; e += 4) {
        unsigned s0 = grec[e], s1 = grec[e + 1], s2 = grec[e + 2], s3 = grec[e + 3];
        float4 v0 = ((const float4*)src)[s0 * 5 + q];
        float4 v1 = ((const float4*)src)[s1 * 5 + q];
        float4 v2 = ((const float4*)src)[s2 * 5 + q];
        float4 v3 = ((const float4*)src)[s3 * 5 + q];
        a0.x += v0.x; a0.y += v0.y; a0.z += v0.z; a0.w += v0.w;
        a1.x += v1.x; a1.y += v1.y; a1.z += v1.z; a1.w += v1.w;
        a2.x += v2.x; a2.y += v2.y; a2.z += v2.z; a2.w += v2.w;
        a3.x += v3.x; a3.y += v3.y; a3.z += v3.z; a3.w += v3.w;
    }
    for (; e < hi; ++e) {
        unsigned s0 = grec[e];
        float4 v0 = ((const float4*)src)[s0 * 5 + q];
        a0.x += v0.x; a0.y += v0.y; a0.z += v0.z; a0.w += v0.w;
    }
    a0.x += a1.x + a2.x + a3.x;
    a0.y += a1.y + a2.y + a3.y;
    a0.z += a1.z + a2.z + a3.z;
    a0.w += a1.w + a2.w + a3.w;
    float sc = rsqrtf(fmaxf((float)(hi - lo), 1.0f));
    a0.x *= sc; a0.y *= sc; a0.z *= sc; a0.w *= sc;
    ((float4*)dst)[node * 5 + q] = a0;
}

// FUSED gc1 + encoder-partials, BALANCED: 11 waves (704 thr).
// Waves 0-2: 7 gc1 pre-activation outputs each (wave2 overlaps at 13,
// duplicate identical write -> branch-free); park in LDS gb[64][21].
// Waves 3-10: encoder octets (8 outputs, W rows 20..276) -> pml bf16.
// Per-chunk FMA 112/112/112/128x8 -> 95% balance (R17 was 47%).
// After loop: barrier; lanes 0-63 do relu/softmax/rs_s -> h_pre.
__global__ __launch_bounds__(704) void k_gc1f(const float* __restrict__ nodes,
                                              const float* __restrict__ W1,
                                              const float* __restrict__ b1,
                                              const float* __restrict__ Wmu,
                                              const float* __restrict__ Wls,
                                              const float* __restrict__ rs_s,
                                              float* __restrict__ h_pre,
                                              unsigned short* __restrict__ pml) {
    __shared__ float tile[64 * 17];    // 4,352 B
    __shared__ float gb[64 * 21];      // 5,376 B  (stride 21: conflict-free)
    int t = threadIdx.x;
    int wave = __builtin_amdgcn_readfirstlane(t >> 6);  // 0..10, scalarized
    int lane = t & 63;
    int n0 = blockIdx.x * 64;
    int node = n0 + lane;

    // gc1 waves (0..2): output base 0,7,13 (wave2 overlaps at 13)
    int jbase = (wave < 2) ? wave * 7 : 13;
    // enc waves (3..10): octet og = wave-3
    int og = wave - 3;
    int half = og >> 2;
    int co = (og & 3) << 3;
    const float* W = half ? Wls : Wmu;

    float acc[8];
#pragma unroll
    for (int j = 0; j < 8; ++j) acc[j] = 0.0f;

    int r = t >> 2, k4 = t & 3;
    for (int ch = 0; ch < 16; ++ch) {
        __syncthreads();
        if (t < 256) {
            int gn = n0 + r;
            float4 v = (gn < N_NODES)
                ? ((const float4*)nodes)[(size_t)gn * 64 + ch * 4 + k4]
                : make_float4(0.f, 0.f, 0.f, 0.f);
            float* dst = &tile[r * 17 + k4 * 4];
            dst[0] = v.x; dst[1] = v.y; dst[2] = v.z; dst[3] = v.w;
        }
        __syncthreads();
        if (wave < 3) {
#pragma unroll
            for (int kk = 0; kk < 16; ++kk) {
                float x = tile[lane * 17 + kk];
                const float* wr = W1 + (ch * 16 + kk) * GC_HID + jbase;
#pragma unroll
                for (int j = 0; j < 7; ++j) acc[j] = fmaf(x, wr[j], acc[j]);
            }
        } else {
#pragma unroll
            for (int kk = 0; kk < 16; ++kk) {
                float x = tile[lane * 17 + kk];
                const float* wr = W + (GC_HID + ch * 16 + kk) * Z_DIM + co;
#pragma unroll
                for (int j = 0; j < 8; ++j) acc[j] = fmaf(x, wr[j], acc[j]);
            }
        }
    }
    // park gc1 pre-activations / emit enc partials
    if (wave < 3) {
        if (node < N_NODES) {
#pragma unroll
            for (int j = 0; j < 7; ++j) gb[lane * 21 + jbase + j] = acc[j] + b1[jbase + j];
        }
    } else if (node < N_NODES) {
        uint4 p;
        p.x = (unsigned)f2bf(acc[0]) | ((unsigned)f2bf(acc[1]) << 16);
        p.y = (unsigned)f2bf(acc[2]) | ((unsigned)f2bf(acc[3]) << 16);
        p.z = (unsigned)f2bf(acc[4]) | ((unsigned)f2bf(acc[5]) << 16);
        p.w = (unsigned)f2bf(acc[6]) | ((unsigned)f2bf(acc[7]) << 16);
        *(uint4*)(pml + (size_t)node * 64 + half * 32 + co) = p;
    }
    __syncthreads();
    // softmax finish: one lane per node
    if (t < 64) {
        int nn = n0 + t;
        if (nn < N_NODES) {
            float v[GC_HID];
            float mx = -1e30f;
#pragma unroll
            for (int j = 0; j < GC_HID; ++j) {
                v[j] = fmaxf(gb[t * 21 + j], 0.0f);
                mx = fmaxf(mx, v[j]);
            }
            float s = 0.0f;
#pragma unroll
            for (int j = 0; j < GC_HID; ++j) {
                v[j] = __expf(v[j] - mx);
                s += v[j];
            }
            float inv = rs_s[nn] / s;
#pragma unroll
            for (int j = 0; j < GC_HID; ++j) v[j] *= inv;
            float4* o = (float4*)&h_pre[(size_t)nn * GC_HID];
            o[0] = make_float4(v[0],  v[1],  v[2],  v[3]);
            o[1] = make_float4(v[4],  v[5],  v[6],  v[7]);
            o[2] = make_float4(v[8],  v[9],  v[10], v[11]);
            o[3] = make_float4(v[12], v[13], v[14], v[15]);
            o[4] = make_float4(v[16], v[17], v[18], v[19]);
        }
    }
}

// GC layer 2 transform: h2_pre = softmax(relu(h1@W2+b2)) * rs_s
__global__ __launch_bounds__(256) void k_gc2(const float* __restrict__ h1in,
                                             const float* __restrict__ W2,
                                             const float* __restrict__ b2,
                                             const float* __restrict__ rs_s,
                                             float* __restrict__ h2_pre) {
    __shared__ float Wsh[GC_HID * GC_HID];
    __shared__ float bsh[GC_HID];
    int tid = threadIdx.x;
    if (tid < GC_HID * GC_HID) Wsh[tid] = W2[tid];
    if (tid < GC_HID) bsh[tid] = b2[tid];
    __syncthreads();
    int node = blockIdx.x * 256 + tid;
    if (node >= N_NODES) return;
    const float4* ap = (const float4*)&h1in[node * GC_HID];
    float4 a0 = ap[0], a1 = ap[1], a2 = ap[2], a3 = ap[3], a4 = ap[4];
    float h1[GC_HID] = {a0.x,a0.y,a0.z,a0.w, a1.x,a1.y,a1.z,a1.w,
                        a2.x,a2.y,a2.z,a2.w, a3.x,a3.y,a3.z,a3.w,
                        a4.x,a4.y,a4.z,a4.w};
    float t[GC_HID];
#pragma unroll
    for (int j = 0; j < GC_HID; ++j) t[j] = bsh[j];
#pragma unroll
    for (int i = 0; i < GC_HID; ++i) {
        float x = h1[i];
#pragma unroll
        for (int j = 0; j < GC_HID; ++j) t[j] = fmaf(x, Wsh[i * GC_HID + j], t[j]);
    }
    float mx = -1e30f;
#pragma unroll
    for (int j = 0; j < GC_HID; ++j) { t[j] = fmaxf(t[j], 0.0f); mx = fmaxf(mx, t[j]); }
    float s = 0.0f;
#pragma unroll
    for (int j = 0; j < GC_HID; ++j) { t[j] = __expf(t[j] - mx); s += t[j]; }
    float inv = rs_s[node] / s;
#pragma unroll
    for (int j = 0; j < GC_HID; ++j) t[j] *= inv;
    float4* o = (float4*)&h2_pre[node * GC_HID];
    o[0] = make_float4(t[0],  t[1],  t[2],  t[3]);
    o[1] = make_float4(t[4],  t[5],  t[6],  t[7]);
    o[2] = make_float4(t[8],  t[9],  t[10], t[11]);
    o[3] = make_float4(t[12], t[13], t[14], t[15]);
    o[4] = make_float4(t[16], t[17], t[18], t[19]);
}

// encoder finish: mu/ls = bias + pml + h2 @ W[0:20]. Octet split,
// grid (1563, 2), block 256 = 4 waves x 64 nodes.
__global__ __launch_bounds__(256) void k_enc2(const float* __restrict__ h2in,
                                              const unsigned short* __restrict__ pml,
                                              const float* __restrict__ Wmu,
                                              const float* __restrict__ bmu,
                                              const float* __restrict__ Wls,
                                              const float* __restrict__ bls,
                                              float* __restrict__ mu_out,
                                              float* __restrict__ ls_out) {
    int t = threadIdx.x;
    int wave = t >> 6, lane = t & 63;
    int og = __builtin_amdgcn_readfirstlane(wave | ((int)blockIdx.y << 2)); // 0..7
    int half = og >> 2;
    int co = (og & 3) << 3;
    int node = blockIdx.x * 64 + lane;
    if (node >= N_NODES) return;
    const float* W  = half ? Wls : Wmu;
    const float* bb = half ? bls : bmu;
    float* out      = half ? ls_out : mu_out;

    uint4 p = *(const uint4*)(pml + (size_t)node * 64 + half * 32 + co);
    float acc[8];
    acc[0] = bf2f((unsigned short)(p.x & 0xFFFFu));
    acc[1] = bf2f((unsigned short)(p.x >> 16));
    acc[2] = bf2f((unsigned short)(p.y & 0xFFFFu));
    acc[3] = bf2f((unsigned short)(p.y >> 16));
    acc[4] = bf2f((unsigned short)(p.z & 0xFFFFu));
    acc[5] = bf2f((unsigned short)(p.z >> 16));
    acc[6] = bf2f((unsigned short)(p.w & 0xFFFFu));
    acc[7] = bf2f((unsigned short)(p.w >> 16));
#pragma unroll
    for (int j = 0; j < 8; ++j) acc[j] += bb[co + j];

    const float4* hp = (const float4*)(h2in + (size_t)node * GC_HID);
#pragma unroll
    for (int v = 0; v < 5; ++v) {
        float4 hh = hp[v];
#pragma unroll
        for (int c = 0; c < 4; ++c) {
            float x = (c == 0) ? hh.x : (c == 1) ? hh.y : (c == 2) ? hh.z : hh.w;
            const float* wr = W + (v * 4 + c) * Z_DIM + co;
#pragma unroll
            for (int j = 0; j < 8; ++j) acc[j] = fmaf(x, wr[j], acc[j]);
        }
    }
    float4* op = (float4*)(out + (size_t)node * Z_DIM + co);
    op[0] = make_float4(acc[0], acc[1], acc[2], acc[3]);
    op[1] = make_float4(acc[4], acc[5], acc[6], acc[7]);
}

// reparameterization: z = mu + (1e-4 + exp(0.5*ls)) * eps
__global__ __launch_bounds__(256) void k_z(const float* __restrict__ mu,
                                           const float* __restrict__ ls,
                                           const float* __restrict__ eps,
                                           float* __restrict__ z) {
    int i = blockIdx.x * 256 + threadIdx.x;
    if (i >= N_NODES * Z_DIM / 4) return;
    float4 m = ((const float4*)mu)[i];
    float4 l = ((const float4*)ls)[i];
    float4 e = ((const float4*)eps)[i];
    float4 zz;
    zz.x = m.x + (1e-4f + __expf(0.5f * l.x)) * e.x;
    zz.y = m.y + (1e-4f + __expf(0.5f * l.y)) * e.y;
    zz.z = m.z + (1e-4f + __expf(0.5f * l.z)) * e.z;
    zz.w = m.w + (1e-4f + __expf(0.5f * l.w)) * e.w;
    ((float4*)z)[i] = zz;
}

// decoder stage 1: d = relu(z@Wd1+bd1), thread per node (weights uniform)
__global__ __launch_bounds__(256) void k_decd(const float* __restrict__ z,
                                              const float* __restrict__ Wd1,
                                              const float* __restrict__ bd1,
                                              float* __restrict__ dbuf) {
    int node = blockIdx.x * 256 + threadIdx.x;
    if (node >= N_NODES) return;
    float d[DEC_HID];
#pragma unroll
    for (int j = 0; j < DEC_HID; ++j) d[j] = bd1[j];
    const float4* zp = (const float4*)(z + (size_t)node * Z_DIM);
#pragma unroll
    for (int v = 0; v < Z_DIM / 4; ++v) {
        float4 zz = zp[v];
#pragma unroll
        for (int c = 0; c < 4; ++c) {
            float x = (c == 0) ? zz.x : (c == 1) ? zz.y : (c == 2) ? zz.z : zz.w;
            const float* wr = Wd1 + (v * 4 + c) * DEC_HID;
#pragma unroll
            for (int j = 0; j < DEC_HID; ++j) d[j] = fmaf(x, wr[j], d[j]);
        }
    }
    float4* op = (float4*)(dbuf + (size_t)node * DEC_HID);
#pragma unroll
    for (int v = 0; v < DEC_HID / 4; ++v)
        op[v] = make_float4(fmaxf(d[4*v], 0.f), fmaxf(d[4*v+1], 0.f),
                            fmaxf(d[4*v+2], 0.f), fmaxf(d[4*v+3], 0.f));
}

// decoder stage 2: chunk id forced wave-uniform via readfirstlane; lane = node.
__global__ __launch_bounds__(256) void k_decx(const float* __restrict__ dbuf,
                                              const float* __restrict__ Wd2,
                                              const float* __restrict__ bd2,
                                              float* __restrict__ X) {
    int lane = threadIdx.x & 63;
    int wv   = threadIdx.x >> 6;             // 0..3
    int ch   = __builtin_amdgcn_readfirstlane(((blockIdx.x & 1) << 2) | wv);
    int node = (blockIdx.x >> 1) * 64 + lane;
    if (node >= N_NODES) return;
    int co = ch << 5;
    float o[32];
#pragma unroll
    for (int j = 0; j < 32; ++j) o[j] = bd2[co + j];
    const float4* dp = (const float4*)(dbuf + (size_t)node * DEC_HID);
#pragma unroll
    for (int v = 0; v < DEC_HID / 4; ++v) {
        float4 dd = dp[v];
#pragma unroll
        for (int c = 0; c < 4; ++c) {
            float x = (c == 0) ? dd.x : (c == 1) ? dd.y : (c == 2) ? dd.z : dd.w;
            const float* wr = Wd2 + (v * 4 + c) * D_FEAT + co;
#pragma unroll
            for (int j = 0; j < 32; ++j) o[j] = fmaf(x, wr[j], o[j]);
        }
    }
    float4* xp = (float4*)(X + (size_t)node * D_FEAT + co);
#pragma unroll
    for (int v = 0; v < 8; ++v)
        xp[v] = make_float4(o[4*v], o[4*v+1], o[4*v+2], o[4*v+3]);
}

extern "C" void kernel_launch(void* const* d_in, const int* in_sizes, int n_in,
                              void* d_out, int out_size, void* d_ws, size_t ws_size,
                              hipStream_t stream) {
    const float* nodes = (const float*)d_in[0];
    const int*   snd   = (const int*)d_in[1];
    const int*   rcv   = (const int*)d_in[2];
    const float* eps   = (const float*)d_in[3];
    const float* W1    = (const float*)d_in[4];
    const float* b1    = (const float*)d_in[5];
    const float* W2    = (const float*)d_in[6];
    const float* b2    = (const float*)d_in[7];
    const float* Wmu   = (const float*)d_in[8];
    const float* bmu   = (const float*)d_in[9];
    const float* Wls   = (const float*)d_in[10];
    const float* bls   = (const float*)d_in[11];
    const float* Wd1   = (const float*)d_in[12];
    const float* bd1   = (const float*)d_in[13];
    const float* Wd2   = (const float*)d_in[14];
    const float* bd2   = (const float*)d_in[15];

    char* ws = (char*)d_ws;
    float*          h_pre    = (float*)(ws);
    float*          agg      = (float*)(ws + 8000000);
    float*          dbuf     = (float*)(ws);              // overlays h_pre+agg (dead)
    unsigned*       grec     = (unsigned*)(ws + 16000000);
    unsigned*       rec_r    = (unsigned*)(ws + 28804096);
    unsigned short* pml      = (unsigned short*)(ws + 28804096); // overlays rec_r post-gscat
    unsigned short* srow_r   = (unsigned short*)(ws + 41608192);
    unsigned*       pref_t   = (unsigned*)(ws + 42836720);
    float*          zbuf     = (float*)(ws + 41608192);   // overlays srow_r/pref_t/row_ptr post-gather
    unsigned*       row_ptr  = (unsigned*)(ws + 45287504);
    unsigned*       gtot     = (unsigned*)(ws + 45687508);
    unsigned*       gbase    = (unsigned*)(ws + 45689076);
    float*          rs_s     = (float*)(ws + 45690648);
    unsigned char*  rec_s    = (unsigned char*)(ws + 46090648);
    unsigned short* srow_s   = (unsigned short*)(ws + 49291672);

    float* X      = (float*)d_out;
    float* mu_out = X + (size_t)N_NODES * D_FEAT;
    float* ls_out = mu_out + (size_t)N_NODES * Z_DIM;

    k_sort<<<NBLK, 512, 0, stream>>>(snd, rcv, rec_r, rec_s, srow_r, srow_s);
    k_degs<<<SB, 512, 0, stream>>>(rec_s, srow_s, rs_s);
    k_scanB<<<SB, 256, 0, stream>>>(srow_r, pref_t, gtot);
    k_scanG<<<1, 512, 0, stream>>>(gtot, gbase);
    k_gscat<<<NBLK, 256, 0, stream>>>(rec_r, srow_r, pref_t, gbase, grec);
    k_sort2<<<SB, 256, 0, stream>>>(grec, gbase, row_ptr);

    // fused gc1 + encoder nodes-partials (nodes read once, balanced waves)
    k_gc1f<<<1563, 704, 0, stream>>>(nodes, W1, b1, Wmu, Wls, rs_s, h_pre, pml);
    k_gather<<<1563, 320, 0, stream>>>(row_ptr, grec, h_pre, agg);
    k_gc2<<<391, 256, 0, stream>>>(agg, W2, b2, rs_s, h_pre);
    k_gather<<<1563, 320, 0, stream>>>(row_ptr, grec, h_pre, agg);

    k_enc2<<<dim3(1563, 2), 256, 0, stream>>>(agg, pml, Wmu, bmu, Wls, bls,
                                              mu_out, ls_out);
    k_z<<<3125, 256, 0, stream>>>(mu_out, ls_out, eps, zbuf);
    k_decd<<<391, 256, 0, stream>>>(zbuf, Wd1, bd1, dbuf);
    k_decx<<<3126, 256, 0, stream>>>(dbuf, Wd2, bd2, X);
}

// Round 19
// 469.982 us; speedup vs baseline: 1.0505x; 1.0473x over previous
//
#include <hip/hip_runtime.h>
#include <math.h>

#define N_NODES 100000
#define N_EDGES 3200000
#define D_FEAT 256
#define GC_HID 20
#define DEC_HID 40
#define Z_DIM 32

#define EPB 2048          // edges per sort block
#define NBLK 1563         // ceil(3.2M / 2048)
#define SB 392            // node buckets of 256 (392*256 = 100352)
#define SBSH 8
#define S2CAP 12288       // per-bucket record cap

// ---------------- ws layout (bytes) ----------------
// h_pre  @ 0           8,000,000
// agg    @ 8,000,000   8,000,000
// dbuf   @ 0          16,000,000   (overlays h_pre+agg when dead)
// grec   @16,000,000  12,804,096
// rec_r  @28,804,096  12,804,096   (pml bf16 overlays post-gscat)
// srow_r @41,608,192   1,228,518   (zbuf overlays post-gather)
// pref_t @42,836,720   2,450,784
// row_ptr@45,287,504     400,004
// gtot   @45,687,508       1,568
// gbase  @45,689,076       1,572
// rs_s   @45,690,648     400,000
// rec_s  @46,090,648   3,201,024
// srow_s @49,291,672   1,228,518   end = 50,520,190

__device__ inline unsigned short f2bf(float f) {
    unsigned u = __float_as_uint(f);
    return (unsigned short)((u + 0x7FFFu + ((u >> 16) & 1u)) >> 16);
}
__device__ inline float bf2f(unsigned short h) {
    return __uint_as_float((unsigned)h << 16);
}

// dual block-local counting sort (receiver u32 + sender u8 streams).
// ZERO global atomics (R13: each device-scope atomic = memory-side write).
__global__ __launch_bounds__(512) void k_sort(const int* __restrict__ snd,
                                              const int* __restrict__ rcv,
                                              unsigned* __restrict__ rec_r,
                                              unsigned char* __restrict__ rec_s,
                                              unsigned short* __restrict__ srow_r,
                                              unsigned short* __restrict__ srow_s) {
    __shared__ int es[EPB], er[EPB];
    __shared__ unsigned scan[SB + 1];
    __shared__ unsigned cur[SB];
    __shared__ unsigned sorted[EPB];
    __shared__ unsigned char sorteds[EPB];
    int b = blockIdx.x, t = threadIdx.x;
    int base = b * EPB;
    int cnt = min(EPB, N_EDGES - base);
    for (int i = t; i < cnt; i += 512) { es[i] = snd[base + i]; er[i] = rcv[base + i]; }

    for (int i = t; i < SB + 1; i += 512) scan[i] = 0u;
    __syncthreads();
    for (int i = t; i < cnt; i += 512) atomicAdd(&scan[(er[i] >> SBSH) + 1], 1u);
    __syncthreads();
    for (int off = 1; off < SB + 1; off <<= 1) {
        unsigned v = (t >= off && t < SB + 1) ? scan[t - off] : 0u;
        __syncthreads();
        if (t < SB + 1) scan[t] += v;
        __syncthreads();
    }
    for (int i = t; i < SB + 1; i += 512) srow_r[(size_t)b * (SB + 1) + i] = (unsigned short)scan[i];
    if (t < SB) cur[t] = scan[t];
    __syncthreads();
    for (int i = t; i < cnt; i += 512) {
        int r = er[i];
        unsigned pos = atomicAdd(&cur[r >> SBSH], 1u);
        sorted[pos] = ((unsigned)(r & 255) << 17) | (unsigned)es[i];
    }
    __syncthreads();
    for (int i = t; i < cnt; i += 512) rec_r[(size_t)base + i] = sorted[i];
    __syncthreads();

    for (int i = t; i < SB + 1; i += 512) scan[i] = 0u;
    __syncthreads();
    for (int i = t; i < cnt; i += 512) atomicAdd(&scan[(es[i] >> SBSH) + 1], 1u);
    __syncthreads();
    for (int off = 1; off < SB + 1; off <<= 1) {
        unsigned v = (t >= off && t < SB + 1) ? scan[t - off] : 0u;
        __syncthreads();
        if (t < SB + 1) scan[t] += v;
        __syncthreads();
    }
    for (int i = t; i < SB + 1; i += 512) srow_s[(size_t)b * (SB + 1) + i] = (unsigned short)scan[i];
    if (t < SB) cur[t] = scan[t];
    __syncthreads();
    for (int i = t; i < cnt; i += 512) {
        int s = es[i];
        unsigned pos = atomicAdd(&cur[s >> SBSH], 1u);
        sorteds[pos] = (unsigned char)(s & 255);
    }
    __syncthreads();
    for (int i = t; i < cnt; i += 512) rec_s[(size_t)base + i] = sorteds[i];
}

// sender-degree via per-bucket LDS histogram over sender-sorted runs
__global__ __launch_bounds__(512) void k_degs(const unsigned char* __restrict__ rec_s,
                                              const unsigned short* __restrict__ srow_s,
                                              float* __restrict__ rs_s) {
    __shared__ unsigned h[256];
    int s = blockIdx.x, t = threadIdx.x;
    if (t < 256) h[t] = 0u;
    __syncthreads();
    for (int k = t; k < NBLK; k += 512) {
        const unsigned short* row = srow_s + (size_t)k * (SB + 1);
        unsigned st = row[s], en = row[s + 1];
        const unsigned char* rp = rec_s + (size_t)k * EPB;
        for (unsigned i = st; i < en; ++i) atomicAdd(&h[rp[i]], 1u);
    }
    __syncthreads();
    if (t < 256) {
        int n = (s << SBSH) + t;
        if (n < N_NODES) rs_s[n] = rsqrtf(fmaxf((float)h[t], 1.0f));
    }
}

// per-bucket prefix over block segments: pref_t[s][k], totals gtot[s]
__global__ __launch_bounds__(256) void k_scanB(const unsigned short* __restrict__ srow_r,
                                               unsigned* __restrict__ pref_t,
                                               unsigned* __restrict__ gtot) {
    __shared__ unsigned buf[256];
    int s = blockIdx.x, t = threadIdx.x;
    unsigned run = 0;
    for (int k0 = 0; k0 < NBLK; k0 += 256) {
        int k = k0 + t;
        unsigned v = 0;
        if (k < NBLK) {
            const unsigned short* row = srow_r + (size_t)k * (SB + 1);
            v = (unsigned)row[s + 1] - (unsigned)row[s];
        }
        buf[t] = v;
        __syncthreads();
        for (int off = 1; off < 256; off <<= 1) {
            unsigned x = (t >= off) ? buf[t - off] : 0u;
            __syncthreads();
            buf[t] += x;
            __syncthreads();
        }
        if (k < NBLK) pref_t[(size_t)s * NBLK + k] = run + (buf[t] - v);
        unsigned tot = buf[255];
        __syncthreads();
        run += tot;
    }
    if (t == 0) gtot[s] = run;
}

// exclusive scan of bucket totals -> gbase[SB+1]
__global__ __launch_bounds__(512) void k_scanG(const unsigned* __restrict__ gtot,
                                               unsigned* __restrict__ gbase) {
    __shared__ unsigned buf[SB];
    int t = threadIdx.x;
    if (t < SB) buf[t] = gtot[t];
    __syncthreads();
    for (int off = 1; off < SB; off <<= 1) {
        unsigned x = (t >= off && t < SB) ? buf[t - off] : 0u;
        __syncthreads();
        if (t < SB) buf[t] += x;
        __syncthreads();
    }
    if (t < SB) gbase[t + 1] = buf[t];
    if (t == 0) gbase[0] = 0u;
}

// scatter block-sorted records to global bucket-sorted order
__global__ __launch_bounds__(256) void k_gscat(const unsigned* __restrict__ rec_r,
                                               const unsigned short* __restrict__ srow_r,
                                               const unsigned* __restrict__ pref_t,
                                               const unsigned* __restrict__ gbase,
                                               unsigned* __restrict__ grec) {
    __shared__ unsigned recs[EPB];
    __shared__ unsigned short srow[SB + 1];
    int b = blockIdx.x, t = threadIdx.x;
    int base = b * EPB;
    int cnt = min(EPB, N_EDGES - base);
    for (int i = t; i < cnt; i += 256) recs[i] = rec_r[(size_t)base + i];
    for (int i = t; i < SB + 1; i += 256) srow[i] = srow_r[(size_t)b * (SB + 1) + i];
    __syncthreads();
    for (int s = t; s < SB; s += 256) {
        unsigned lo = srow[s], hi = srow[s + 1];
        if (lo == hi) continue;
        unsigned dst = gbase[s] + pref_t[(size_t)s * NBLK + b];
        for (unsigned i = lo; i < hi; ++i) grec[dst + (i - lo)] = recs[i];
    }
}

// within-bucket counting sort by local receiver (in-place) + CSR row_ptr
__global__ __launch_bounds__(256) void k_sort2(unsigned* __restrict__ grec,
                                               const unsigned* __restrict__ gbase,
                                               unsigned* __restrict__ row_ptr) {
    __shared__ unsigned recs[S2CAP];     // 48 KB
    __shared__ unsigned hist[256];
    __shared__ unsigned scan[256];
    __shared__ unsigned cur[256];
    int s = blockIdx.x, t = threadIdx.x;
    unsigned lo = gbase[s], hi = gbase[s + 1];
    unsigned cnt = min(hi - lo, (unsigned)S2CAP);
    for (unsigned i = t; i < cnt; i += 256) recs[i] = grec[lo + i];
    hist[t] = 0u;
    __syncthreads();
    for (unsigned i = t; i < cnt; i += 256) atomicAdd(&hist[recs[i] >> 17], 1u);
    __syncthreads();
    unsigned v = hist[t];
    scan[t] = v;
    __syncthreads();
    for (int off = 1; off < 256; off <<= 1) {
        unsigned x = (t >= off) ? scan[t - off] : 0u;
        __syncthreads();
        scan[t] += x;
        __syncthreads();
    }
    unsigned excl = scan[t] - v;
    {
        int n = (s << SBSH) + t;
        if (n <= N_NODES) row_ptr[n] = lo + excl;
    }
    cur[t] = excl;
    __syncthreads();
    for (unsigned i = t; i < cnt; i += 256) {
        unsigned rec = recs[i];
        unsigned pos = atomicAdd(&cur[rec >> 17], 1u);
        grec[lo + pos] = rec & 0x1FFFFu;
    }
}

// pure CSR gather: 5 lanes per node, one float4 each; zero atomics.
__global__ __launch_bounds__(320) void k_gather(const unsigned* __restrict__ row_ptr,
                                                const unsigned* __restrict__ grec,
                                                const float* __restrict__ src,
                                                float* __restrict__ dst) {
    int gid = blockIdx.x * 320 + threadIdx.x;
    int node = gid / 5, q = gid % 5;
    if (node >= N_NODES) return;
    unsigned lo = row_ptr[node], hi = row_ptr[node + 1];
    float4 a0 = make_float4(0.f, 0.f, 0.f, 0.f);
    float4 a1 = make_float4(0.f, 0.f, 0.f, 0.f);
    float4 a2 = make_float4(0.f, 0.f, 0.f, 0.f);
    float4 a3 = make_float4(0.f, 0.f, 0.f, 0.f);
    unsigned e = lo;
    for (; e + 4 <= hi; e += 4) {
        unsigned s0 = grec[e], s1 = grec[e + 1], s2 = grec[e + 2], s3 = grec[e + 3];
        float4 v0 = ((const float4*)src)[s0 * 5 + q];
        float4 v1 = ((const float4*)src)[s1 * 5 + q];
        float4 v2 = ((const float4*)src)[s2 * 5 + q];
        float4 v3 = ((const float4*)src)[s3 * 5 + q];
        a0.x += v0.x; a0.y += v0.y; a0.z += v0.z; a0.w += v0.w;
        a1.x += v1.x; a1.y += v1.y; a1.z += v1.z; a1.w += v1.w;
        a2.x += v2.x; a2.y += v2.y; a2.z += v2.z; a2.w += v2.w;
        a3.x += v3.x; a3.y += v3.y; a3.z += v3.z; a3.w += v3.w;
    }
    for (; e < hi; ++e) {
        unsigned s0 = grec[e];
        float4 v0 = ((const float4*)src)[s0 * 5 + q];
        a0.x += v0.x; a0.y += v0.y; a0.z += v0.z; a0.w += v0.w;
    }
    a0.x += a1.x + a2.x + a3.x;
    a0.y += a1.y + a2.y + a3.y;
    a0.z += a1.z + a2.z + a3.z;
    a0.w += a1.w + a2.w + a3.w;
    float sc = rsqrtf(fmaxf((float)(hi - lo), 1.0f));
    a0.x *= sc; a0.y *= sc; a0.z *= sc; a0.w *= sc;
    ((float4*)dst)[node * 5 + q] = a0;
}

// FUSED gc1 + encoder-partials, FULL-TILE STAGE: stage the entire
// 64x256 node tile once (stride 257 -> (i+k)%32 banks, 2-way = free),
// ONE barrier, then 256 k-steps of pure FMA (no further syncs).
// R18 lesson: 32 barriers x HBM-latency was the cost, not wave balance.
// 11 waves: 0-2 gc1 (7 outs each, wave2 base 13), 3-10 enc octets.
__global__ __launch_bounds__(704) void k_gc1f(const float* __restrict__ nodes,
                                              const float* __restrict__ W1,
                                              const float* __restrict__ b1,
                                              const float* __restrict__ Wmu,
                                              const float* __restrict__ Wls,
                                              const float* __restrict__ rs_s,
                                              float* __restrict__ h_pre,
                                              unsigned short* __restrict__ pml) {
    __shared__ float tile[64 * 257];   // 65,792 B
    __shared__ float gb[64 * 21];      // 5,376 B
    int t = threadIdx.x;
    int wave = __builtin_amdgcn_readfirstlane(t >> 6);  // 0..10, scalarized
    int lane = t & 63;
    int n0 = blockIdx.x * 64;
    int node = n0 + lane;

    int jbase = (wave < 2) ? wave * 7 : 13;   // gc1 waves: 0,7,13 (overlap@13)
    int og = wave - 3;                         // enc waves
    int half = og >> 2;
    int co = (og & 3) << 3;
    const float* W = half ? Wls : Wmu;

    // ---- stage whole tile: 4096 float4, coalesced 1KB per wave-read ----
    for (int idx = t; idx < 4096; idx += 704) {
        int row = idx >> 6, c4 = idx & 63;
        int gn = n0 + row;
        float4 v = (gn < N_NODES)
            ? ((const float4*)nodes)[(size_t)gn * 64 + c4]
            : make_float4(0.f, 0.f, 0.f, 0.f);
        float* dst = &tile[row * 257 + c4 * 4];
        dst[0] = v.x; dst[1] = v.y; dst[2] = v.z; dst[3] = v.w;
    }
    __syncthreads();

    float acc[8];
#pragma unroll
    for (int j = 0; j < 8; ++j) acc[j] = 0.0f;

    const float* trow = &tile[lane * 257];
    if (wave < 3) {
        for (int k0 = 0; k0 < 256; k0 += 16) {
#pragma unroll
            for (int kk = 0; kk < 16; ++kk) {
                float x = trow[k0 + kk];
                const float* wr = W1 + (k0 + kk) * GC_HID + jbase;
#pragma unroll
                for (int j = 0; j < 7; ++j) acc[j] = fmaf(x, wr[j], acc[j]);
            }
        }
        if (node < N_NODES) {
#pragma unroll
            for (int j = 0; j < 7; ++j) gb[lane * 21 + jbase + j] = acc[j] + b1[jbase + j];
        }
    } else {
        for (int k0 = 0; k0 < 256; k0 += 16) {
#pragma unroll
            for (int kk = 0; kk < 16; ++kk) {
                float x = trow[k0 + kk];
                const float* wr = W + (GC_HID + k0 + kk) * Z_DIM + co;
#pragma unroll
                for (int j = 0; j < 8; ++j) acc[j] = fmaf(x, wr[j], acc[j]);
            }
        }
        if (node < N_NODES) {
            uint4 p;
            p.x = (unsigned)f2bf(acc[0]) | ((unsigned)f2bf(acc[1]) << 16);
            p.y = (unsigned)f2bf(acc[2]) | ((unsigned)f2bf(acc[3]) << 16);
            p.z = (unsigned)f2bf(acc[4]) | ((unsigned)f2bf(acc[5]) << 16);
            p.w = (unsigned)f2bf(acc[6]) | ((unsigned)f2bf(acc[7]) << 16);
            *(uint4*)(pml + (size_t)node * 64 + half * 32 + co) = p;
        }
    }
    __syncthreads();
    // softmax finish: one lane per node
    if (t < 64) {
        int nn = n0 + t;
        if (nn < N_NODES) {
            float v[GC_HID];
            float mx = -1e30f;
#pragma unroll
            for (int j = 0; j < GC_HID; ++j) {
                v[j] = fmaxf(gb[t * 21 + j], 0.0f);
                mx = fmaxf(mx, v[j]);
            }
            float s = 0.0f;
#pragma unroll
            for (int j = 0; j < GC_HID; ++j) {
                v[j] = __expf(v[j] - mx);
                s += v[j];
            }
            float inv = rs_s[nn] / s;
#pragma unroll
            for (int j = 0; j < GC_HID; ++j) v[j] *= inv;
            float4* o = (float4*)&h_pre[(size_t)nn * GC_HID];
            o[0] = make_float4(v[0],  v[1],  v[2],  v[3]);
            o[1] = make_float4(v[4],  v[5],  v[6],  v[7]);
            o[2] = make_float4(v[8],  v[9],  v[10], v[11]);
            o[3] = make_float4(v[12], v[13], v[14], v[15]);
            o[4] = make_float4(v[16], v[17], v[18], v[19]);
        }
    }
}

// GC layer 2 transform: h2_pre = softmax(relu(h1@W2+b2)) * rs_s
__global__ __launch_bounds__(256) void k_gc2(const float* __restrict__ h1in,
                                             const float* __restrict__ W2,
                                             const float* __restrict__ b2,
                                             const float* __restrict__ rs_s,
                                             float* __restrict__ h2_pre) {
    __shared__ float Wsh[GC_HID * GC_HID];
    __shared__ float bsh[GC_HID];
    int tid = threadIdx.x;
    if (tid < GC_HID * GC_HID) Wsh[tid] = W2[tid];
    if (tid < GC_HID) bsh[tid] = b2[tid];
    __syncthreads();
    int node = blockIdx.x * 256 + tid;
    if (node >= N_NODES) return;
    const float4* ap = (const float4*)&h1in[node * GC_HID];
    float4 a0 = ap[0], a1 = ap[1], a2 = ap[2], a3 = ap[3], a4 = ap[4];
    float h1[GC_HID] = {a0.x,a0.y,a0.z,a0.w, a1.x,a1.y,a1.z,a1.w,
                        a2.x,a2.y,a2.z,a2.w, a3.x,a3.y,a3.z,a3.w,
                        a4.x,a4.y,a4.z,a4.w};
    float t[GC_HID];
#pragma unroll
    for (int j = 0; j < GC_HID; ++j) t[j] = bsh[j];
#pragma unroll
    for (int i = 0; i < GC_HID; ++i) {
        float x = h1[i];
#pragma unroll
        for (int j = 0; j < GC_HID; ++j) t[j] = fmaf(x, Wsh[i * GC_HID + j], t[j]);
    }
    float mx = -1e30f;
#pragma unroll
    for (int j = 0; j < GC_HID; ++j) { t[j] = fmaxf(t[j], 0.0f); mx = fmaxf(mx, t[j]); }
    float s = 0.0f;
#pragma unroll
    for (int j = 0; j < GC_HID; ++j) { t[j] = __expf(t[j] - mx); s += t[j]; }
    float inv = rs_s[node] / s;
#pragma unroll
    for (int j = 0; j < GC_HID; ++j) t[j] *= inv;
    float4* o = (float4*)&h2_pre[node * GC_HID];
    o[0] = make_float4(t[0],  t[1],  t[2],  t[3]);
    o[1] = make_float4(t[4],  t[5],  t[6],  t[7]);
    o[2] = make_float4(t[8],  t[9],  t[10], t[11]);
    o[3] = make_float4(t[12], t[13], t[14], t[15]);
    o[4] = make_float4(t[16], t[17], t[18], t[19]);
}

// encoder finish: mu/ls = bias + pml + h2 @ W[0:20]. Octet split,
// grid (1563, 2), block 256 = 4 waves x 64 nodes.
__global__ __launch_bounds__(256) void k_enc2(const float* __restrict__ h2in,
                                              const unsigned short* __restrict__ pml,
                                              const float* __restrict__ Wmu,
                                              const float* __restrict__ bmu,
                                              const float* __restrict__ Wls,
                                              const float* __restrict__ bls,
                                              float* __restrict__ mu_out,
                                              float* __restrict__ ls_out) {
    int t = threadIdx.x;
    int wave = t >> 6, lane = t & 63;
    int og = __builtin_amdgcn_readfirstlane(wave | ((int)blockIdx.y << 2)); // 0..7
    int half = og >> 2;
    int co = (og & 3) << 3;
    int node = blockIdx.x * 64 + lane;
    if (node >= N_NODES) return;
    const float* W  = half ? Wls : Wmu;
    const float* bb = half ? bls : bmu;
    float* out      = half ? ls_out : mu_out;

    uint4 p = *(const uint4*)(pml + (size_t)node * 64 + half * 32 + co);
    float acc[8];
    acc[0] = bf2f((unsigned short)(p.x & 0xFFFFu));
    acc[1] = bf2f((unsigned short)(p.x >> 16));
    acc[2] = bf2f((unsigned short)(p.y & 0xFFFFu));
    acc[3] = bf2f((unsigned short)(p.y >> 16));
    acc[4] = bf2f((unsigned short)(p.z & 0xFFFFu));
    acc[5] = bf2f((unsigned short)(p.z >> 16));
    acc[6] = bf2f((unsigned short)(p.w & 0xFFFFu));
    acc[7] = bf2f((unsigned short)(p.w >> 16));
#pragma unroll
    for (int j = 0; j < 8; ++j) acc[j] += bb[co + j];

    const float4* hp = (const float4*)(h2in + (size_t)node * GC_HID);
#pragma unroll
    for (int v = 0; v < 5; ++v) {
        float4 hh = hp[v];
#pragma unroll
        for (int c = 0; c < 4; ++c) {
            float x = (c == 0) ? hh.x : (c == 1) ? hh.y : (c == 2) ? hh.z : hh.w;
            const float* wr = W + (v * 4 + c) * Z_DIM + co;
#pragma unroll
            for (int j = 0; j < 8; ++j) acc[j] = fmaf(x, wr[j], acc[j]);
        }
    }
    float4* op = (float4*)(out + (size_t)node * Z_DIM + co);
    op[0] = make_float4(acc[0], acc[1], acc[2], acc[3]);
    op[1] = make_float4(acc[4], acc[5], acc[6], acc[7]);
}

// reparameterization: z = mu + (1e-4 + exp(0.5*ls)) * eps
__global__ __launch_bounds__(256) void k_z(const float* __restrict__ mu,
                                           const float* __restrict__ ls,
                                           const float* __restrict__ eps,
                                           float* __restrict__ z) {
    int i = blockIdx.x * 256 + threadIdx.x;
    if (i >= N_NODES * Z_DIM / 4) return;
    float4 m = ((const float4*)mu)[i];
    float4 l = ((const float4*)ls)[i];
    float4 e = ((const float4*)eps)[i];
    float4 zz;
    zz.x = m.x + (1e-4f + __expf(0.5f * l.x)) * e.x;
    zz.y = m.y + (1e-4f + __expf(0.5f * l.y)) * e.y;
    zz.z = m.z + (1e-4f + __expf(0.5f * l.z)) * e.z;
    zz.w = m.w + (1e-4f + __expf(0.5f * l.w)) * e.w;
    ((float4*)z)[i] = zz;
}

// decoder stage 1: d = relu(z@Wd1+bd1), thread per node (weights uniform)
__global__ __launch_bounds__(256) void k_decd(const float* __restrict__ z,
                                              const float* __restrict__ Wd1,
                                              const float* __restrict__ bd1,
                                              float* __restrict__ dbuf) {
    int node = blockIdx.x * 256 + threadIdx.x;
    if (node >= N_NODES) return;
    float d[DEC_HID];
#pragma unroll
    for (int j = 0; j < DEC_HID; ++j) d[j] = bd1[j];
    const float4* zp = (const float4*)(z + (size_t)node * Z_DIM);
#pragma unroll
    for (int v = 0; v < Z_DIM / 4; ++v) {
        float4 zz = zp[v];
#pragma unroll
        for (int c = 0; c < 4; ++c) {
            float x = (c == 0) ? zz.x : (c == 1) ? zz.y : (c == 2) ? zz.z : zz.w;
            const float* wr = Wd1 + (v * 4 + c) * DEC_HID;
#pragma unroll
            for (int j = 0; j < DEC_HID; ++j) d[j] = fmaf(x, wr[j], d[j]);
        }
    }
    float4* op = (float4*)(dbuf + (size_t)node * DEC_HID);
#pragma unroll
    for (int v = 0; v < DEC_HID / 4; ++v)
        op[v] = make_float4(fmaxf(d[4*v], 0.f), fmaxf(d[4*v+1], 0.f),
                            fmaxf(d[4*v+2], 0.f), fmaxf(d[4*v+3], 0.f));
}

// decoder stage 2: chunk id forced wave-uniform via readfirstlane; lane = node.
__global__ __launch_bounds__(256) void k_decx(const float* __restrict__ dbuf,
                                              const float* __restrict__ Wd2,
                                              const float* __restrict__ bd2,
                                              float* __restrict__ X) {
    int lane = threadIdx.x & 63;
    int wv   = threadIdx.x >> 6;             // 0..3
    int ch   = __builtin_amdgcn_readfirstlane(((blockIdx.x & 1) << 2) | wv);
    int node = (blockIdx.x >> 1) * 64 + lane;
    if (node >= N_NODES) return;
    int co = ch << 5;
    float o[32];
#pragma unroll
    for (int j = 0; j < 32; ++j) o[j] = bd2[co + j];
    const float4* dp = (const float4*)(dbuf + (size_t)node * DEC_HID);
#pragma unroll
    for (int v = 0; v < DEC_HID / 4; ++v) {
        float4 dd = dp[v];
#pragma unroll
        for (int c = 0; c < 4; ++c) {
            float x = (c == 0) ? dd.x : (c == 1) ? dd.y : (c == 2) ? dd.z : dd.w;
            const float* wr = Wd2 + (v * 4 + c) * D_FEAT + co;
#pragma unroll
            for (int j = 0; j < 32; ++j) o[j] = fmaf(x, wr[j], o[j]);
        }
    }
    float4* xp = (float4*)(X + (size_t)node * D_FEAT + co);
#pragma unroll
    for (int v = 0; v < 8; ++v)
        xp[v] = make_float4(o[4*v], o[4*v+1], o[4*v+2], o[4*v+3]);
}

extern "C" void kernel_launch(void* const* d_in, const int* in_sizes, int n_in,
                              void* d_out, int out_size, void* d_ws, size_t ws_size,
                              hipStream_t stream) {
    const float* nodes = (const float*)d_in[0];
    const int*   snd   = (const int*)d_in[1];
    const int*   rcv   = (const int*)d_in[2];
    const float* eps   = (const float*)d_in[3];
    const float* W1    = (const float*)d_in[4];
    const float* b1    = (const float*)d_in[5];
    const float* W2    = (const float*)d_in[6];
    const float* b2    = (const float*)d_in[7];
    const float* Wmu   = (const float*)d_in[8];
    const float* bmu   = (const float*)d_in[9];
    const float* Wls   = (const float*)d_in[10];
    const float* bls   = (const float*)d_in[11];
    const float* Wd1   = (const float*)d_in[12];
    const float* bd1   = (const float*)d_in[13];
    const float* Wd2   = (const float*)d_in[14];
    const float* bd2   = (const float*)d_in[15];

    char* ws = (char*)d_ws;
    float*          h_pre    = (float*)(ws);
    float*          agg      = (float*)(ws + 8000000);
    float*          dbuf     = (float*)(ws);              // overlays h_pre+agg (dead)
    unsigned*       grec     = (unsigned*)(ws + 16000000);
    unsigned*       rec_r    = (unsigned*)(ws + 28804096);
    unsigned short* pml      = (unsigned short*)(ws + 28804096); // overlays rec_r post-gscat
    unsigned short* srow_r   = (unsigned short*)(ws + 41608192);
    unsigned*       pref_t   = (unsigned*)(ws + 42836720);
    float*          zbuf     = (float*)(ws + 41608192);   // overlays srow_r/pref_t/row_ptr post-gather
    unsigned*       row_ptr  = (unsigned*)(ws + 45287504);
    unsigned*       gtot     = (unsigned*)(ws + 45687508);
    unsigned*       gbase    = (unsigned*)(ws + 45689076);
    float*          rs_s     = (float*)(ws + 45690648);
    unsigned char*  rec_s    = (unsigned char*)(ws + 46090648);
    unsigned short* srow_s   = (unsigned short*)(ws + 49291672);

    float* X      = (float*)d_out;
    float* mu_out = X + (size_t)N_NODES * D_FEAT;
    float* ls_out = mu_out + (size_t)N_NODES * Z_DIM;

    k_sort<<<NBLK, 512, 0, stream>>>(snd, rcv, rec_r, rec_s, srow_r, srow_s);
    k_degs<<<SB, 512, 0, stream>>>(rec_s, srow_s, rs_s);
    k_scanB<<<SB, 256, 0, stream>>>(srow_r, pref_t, gtot);
    k_scanG<<<1, 512, 0, stream>>>(gtot, gbase);
    k_gscat<<<NBLK, 256, 0, stream>>>(rec_r, srow_r, pref_t, gbase, grec);
    k_sort2<<<SB, 256, 0, stream>>>(grec, gbase, row_ptr);

    // fused gc1 + encoder nodes-partials (nodes read once, single barrier)
    k_gc1f<<<1563, 704, 0, stream>>>(nodes, W1, b1, Wmu, Wls, rs_s, h_pre, pml);
    k_gather<<<1563, 320, 0, stream>>>(row_ptr, grec, h_pre, agg);
    k_gc2<<<391, 256, 0, stream>>>(agg, W2, b2, rs_s, h_pre);
    k_gather<<<1563, 320, 0, stream>>>(row_ptr, grec, h_pre, agg);

    k_enc2<<<dim3(1563, 2), 256, 0, stream>>>(agg, pml, Wmu, bmu, Wls, bls,
                                              mu_out, ls_out);
    k_z<<<3125, 256, 0, stream>>>(mu_out, ls_out, eps, zbuf);
    k_decd<<<391, 256, 0, stream>>>(zbuf, Wd1, bd1, dbuf);
    k_decx<<<3126, 256, 0, stream>>>(dbuf, Wd2, bd2, X);
}

// Round 20
// 428.169 us; speedup vs baseline: 1.1531x; 1.0977x over previous
//
#include <hip/hip_runtime.h>
#include <math.h>

#define N_NODES 100000
#define N_EDGES 3200000
#define D_FEAT 256
#define GC_HID 20
#define DEC_HID 40
#define Z_DIM 32

#define EPB 2048          // edges per sort block
#define NBLK 1563         // ceil(3.2M / 2048)
#define SB 392            // node buckets of 256 (392*256 = 100352)
#define SBSH 8
#define S2CAP 12288       // per-bucket record cap

// ---------------- ws layout (bytes) ----------------
// h_pre  @ 0           8,000,000
// agg    @ 8,000,000   8,000,000
// dbuf   @ 0          16,000,000   (overlays h_pre+agg when dead)
// grec   @16,000,000  12,804,096
// rec_r  @28,804,096  12,804,096   (pml bf16 [N][64]=12.8MB overlays post-gscat)
// srow_r @41,608,192   1,228,518   (zbuf overlays post-gather)
// pref_t @42,836,720   2,450,784
// row_ptr@45,287,504     400,004
// gtot   @45,687,508       1,568
// gbase  @45,689,076       1,572
// rs_s   @45,690,648     400,000
// rec_s  @46,090,648   3,201,024
// srow_s @49,291,672   1,228,518
// Wpack  @50,520,192      98,304   end = 50,618,496

__device__ inline unsigned short f2bf(float f) {
    unsigned u = __float_as_uint(f);
    return (unsigned short)((u + 0x7FFFu + ((u >> 16) & 1u)) >> 16);
}
__device__ inline float bf2f(unsigned short h) {
    return __uint_as_float((unsigned)h << 16);
}

// pack node-row weights: Wpack[k][0:20]=W1[k], [24:56]=Wmu[20+k], [56:88]=Wls[20+k]
__global__ __launch_bounds__(96) void k_wpack(const float* __restrict__ W1,
                                              const float* __restrict__ Wmu,
                                              const float* __restrict__ Wls,
                                              float* __restrict__ Wp) {
    int k = blockIdx.x, j = threadIdx.x;
    float v = 0.0f;
    if (j < 20) v = W1[k * GC_HID + j];
    else if (j >= 24 && j < 56) v = Wmu[(GC_HID + k) * Z_DIM + (j - 24)];
    else if (j >= 56 && j < 88) v = Wls[(GC_HID + k) * Z_DIM + (j - 56)];
    Wp[k * 96 + j] = v;
}

// dual block-local counting sort (receiver u32 + sender u8 streams).
// ZERO global atomics (R13: each device-scope atomic = memory-side write).
__global__ __launch_bounds__(512) void k_sort(const int* __restrict__ snd,
                                              const int* __restrict__ rcv,
                                              unsigned* __restrict__ rec_r,
                                              unsigned char* __restrict__ rec_s,
                                              unsigned short* __restrict__ srow_r,
                                              unsigned short* __restrict__ srow_s) {
    __shared__ int es[EPB], er[EPB];
    __shared__ unsigned scan[SB + 1];
    __shared__ unsigned cur[SB];
    __shared__ unsigned sorted[EPB];
    __shared__ unsigned char sorteds[EPB];
    int b = blockIdx.x, t = threadIdx.x;
    int base = b * EPB;
    int cnt = min(EPB, N_EDGES - base);
    for (int i = t; i < cnt; i += 512) { es[i] = snd[base + i]; er[i] = rcv[base + i]; }

    for (int i = t; i < SB + 1; i += 512) scan[i] = 0u;
    __syncthreads();
    for (int i = t; i < cnt; i += 512) atomicAdd(&scan[(er[i] >> SBSH) + 1], 1u);
    __syncthreads();
    for (int off = 1; off < SB + 1; off <<= 1) {
        unsigned v = (t >= off && t < SB + 1) ? scan[t - off] : 0u;
        __syncthreads();
        if (t < SB + 1) scan[t] += v;
        __syncthreads();
    }
    for (int i = t; i < SB + 1; i += 512) srow_r[(size_t)b * (SB + 1) + i] = (unsigned short)scan[i];
    if (t < SB) cur[t] = scan[t];
    __syncthreads();
    for (int i = t; i < cnt; i += 512) {
        int r = er[i];
        unsigned pos = atomicAdd(&cur[r >> SBSH], 1u);
        sorted[pos] = ((unsigned)(r & 255) << 17) | (unsigned)es[i];
    }
    __syncthreads();
    for (int i = t; i < cnt; i += 512) rec_r[(size_t)base + i] = sorted[i];
    __syncthreads();

    for (int i = t; i < SB + 1; i += 512) scan[i] = 0u;
    __syncthreads();
    for (int i = t; i < cnt; i += 512) atomicAdd(&scan[(es[i] >> SBSH) + 1], 1u);
    __syncthreads();
    for (int off = 1; off < SB + 1; off <<= 1) {
        unsigned v = (t >= off && t < SB + 1) ? scan[t - off] : 0u;
        __syncthreads();
        if (t < SB + 1) scan[t] += v;
        __syncthreads();
    }
    for (int i = t; i < SB + 1; i += 512) srow_s[(size_t)b * (SB + 1) + i] = (unsigned short)scan[i];
    if (t < SB) cur[t] = scan[t];
    __syncthreads();
    for (int i = t; i < cnt; i += 512) {
        int s = es[i];
        unsigned pos = atomicAdd(&cur[s >> SBSH], 1u);
        sorteds[pos] = (unsigned char)(s & 255);
    }
    __syncthreads();
    for (int i = t; i < cnt; i += 512) rec_s[(size_t)base + i] = sorteds[i];
}

// sender-degree via per-bucket LDS histogram over sender-sorted runs
__global__ __launch_bounds__(512) void k_degs(const unsigned char* __restrict__ rec_s,
                                              const unsigned short* __restrict__ srow_s,
                                              float* __restrict__ rs_s) {
    __shared__ unsigned h[256];
    int s = blockIdx.x, t = threadIdx.x;
    if (t < 256) h[t] = 0u;
    __syncthreads();
    for (int k = t; k < NBLK; k += 512) {
        const unsigned short* row = srow_s + (size_t)k * (SB + 1);
        unsigned st = row[s], en = row[s + 1];
        const unsigned char* rp = rec_s + (size_t)k * EPB;
        for (unsigned i = st; i < en; ++i) atomicAdd(&h[rp[i]], 1u);
    }
    __syncthreads();
    if (t < 256) {
        int n = (s << SBSH) + t;
        if (n < N_NODES) rs_s[n] = rsqrtf(fmaxf((float)h[t], 1.0f));
    }
}

// per-bucket prefix over block segments: pref_t[s][k], totals gtot[s]
__global__ __launch_bounds__(256) void k_scanB(const unsigned short* __restrict__ srow_r,
                                               unsigned* __restrict__ pref_t,
                                               unsigned* __restrict__ gtot) {
    __shared__ unsigned buf[256];
    int s = blockIdx.x, t = threadIdx.x;
    unsigned run = 0;
    for (int k0 = 0; k0 < NBLK; k0 += 256) {
        int k = k0 + t;
        unsigned v = 0;
        if (k < NBLK) {
            const unsigned short* row = srow_r + (size_t)k * (SB + 1);
            v = (unsigned)row[s + 1] - (unsigned)row[s];
        }
        buf[t] = v;
        __syncthreads();
        for (int off = 1; off < 256; off <<= 1) {
            unsigned x = (t >= off) ? buf[t - off] : 0u;
            __syncthreads();
            buf[t] += x;
            __syncthreads();
        }
        if (k < NBLK) pref_t[(size_t)s * NBLK + k] = run + (buf[t] - v);
        unsigned tot = buf[255];
        __syncthreads();
        run += tot;
    }
    if (t == 0) gtot[s] = run;
}

// exclusive scan of bucket totals -> gbase[SB+1]
__global__ __launch_bounds__(512) void k_scanG(const unsigned* __restrict__ gtot,
                                               unsigned* __restrict__ gbase) {
    __shared__ unsigned buf[SB];
    int t = threadIdx.x;
    if (t < SB) buf[t] = gtot[t];
    __syncthreads();
    for (int off = 1; off < SB; off <<= 1) {
        unsigned x = (t >= off && t < SB) ? buf[t - off] : 0u;
        __syncthreads();
        if (t < SB) buf[t] += x;
        __syncthreads();
    }
    if (t < SB) gbase[t + 1] = buf[t];
    if (t == 0) gbase[0] = 0u;
}

// scatter block-sorted records to global bucket-sorted order
__global__ __launch_bounds__(256) void k_gscat(const unsigned* __restrict__ rec_r,
                                               const unsigned short* __restrict__ srow_r,
                                               const unsigned* __restrict__ pref_t,
                                               const unsigned* __restrict__ gbase,
                                               unsigned* __restrict__ grec) {
    __shared__ unsigned recs[EPB];
    __shared__ unsigned short srow[SB + 1];
    int b = blockIdx.x, t = threadIdx.x;
    int base = b * EPB;
    int cnt = min(EPB, N_EDGES - base);
    for (int i = t; i < cnt; i += 256) recs[i] = rec_r[(size_t)base + i];
    for (int i = t; i < SB + 1; i += 256) srow[i] = srow_r[(size_t)b * (SB + 1) + i];
    __syncthreads();
    for (int s = t; s < SB; s += 256) {
        unsigned lo = srow[s], hi = srow[s + 1];
        if (lo == hi) continue;
        unsigned dst = gbase[s] + pref_t[(size_t)s * NBLK + b];
        for (unsigned i = lo; i < hi; ++i) grec[dst + (i - lo)] = recs[i];
    }
}

// within-bucket counting sort by local receiver (in-place) + CSR row_ptr
__global__ __launch_bounds__(256) void k_sort2(unsigned* __restrict__ grec,
                                               const unsigned* __restrict__ gbase,
                                               unsigned* __restrict__ row_ptr) {
    __shared__ unsigned recs[S2CAP];     // 48 KB
    __shared__ unsigned hist[256];
    __shared__ unsigned scan[256];
    __shared__ unsigned cur[256];
    int s = blockIdx.x, t = threadIdx.x;
    unsigned lo = gbase[s], hi = gbase[s + 1];
    unsigned cnt = min(hi - lo, (unsigned)S2CAP);
    for (unsigned i = t; i < cnt; i += 256) recs[i] = grec[lo + i];
    hist[t] = 0u;
    __syncthreads();
    for (unsigned i = t; i < cnt; i += 256) atomicAdd(&hist[recs[i] >> 17], 1u);
    __syncthreads();
    unsigned v = hist[t];
    scan[t] = v;
    __syncthreads();
    for (int off = 1; off < 256; off <<= 1) {
        unsigned x = (t >= off) ? scan[t - off] : 0u;
        __syncthreads();
        scan[t] += x;
        __syncthreads();
    }
    unsigned excl = scan[t] - v;
    {
        int n = (s << SBSH) + t;
        if (n <= N_NODES) row_ptr[n] = lo + excl;
    }
    cur[t] = excl;
    __syncthreads();
    for (unsigned i = t; i < cnt; i += 256) {
        unsigned rec = recs[i];
        unsigned pos = atomicAdd(&cur[rec >> 17], 1u);
        grec[lo + pos] = rec & 0x1FFFFu;
    }
}

// pure CSR gather: 5 lanes per node, one float4 each; zero atomics.
__global__ __launch_bounds__(320) void k_gather(const unsigned* __restrict__ row_ptr,
                                                const unsigned* __restrict__ grec,
                                                const float* __restrict__ src,
                                                float* __restrict__ dst) {
    int gid = blockIdx.x * 320 + threadIdx.x;
    int node = gid / 5, q = gid % 5;
    if (node >= N_NODES) return;
    unsigned lo = row_ptr[node], hi = row_ptr[node + 1];
    float4 a0 = make_float4(0.f, 0.f, 0.f, 0.f);
    float4 a1 = make_float4(0.f, 0.f, 0.f, 0.f);
    float4 a2 = make_float4(0.f, 0.f, 0.f, 0.f);
    float4 a3 = make_float4(0.f, 0.f, 0.f, 0.f);
    unsigned e = lo;
    for (; e + 4 <= hi; e += 4) {
        unsigned s0 = grec[e], s1 = grec[e + 1], s2 = grec[e + 2], s3 = grec[e + 3];
        float4 v0 = ((const float4*)src)[s0 * 5 + q];
        float4 v1 = ((const float4*)src)[s1 * 5 + q];
        float4 v2 = ((const float4*)src)[s2 * 5 + q];
        float4 v3 = ((const float4*)src)[s3 * 5 + q];
        a0.x += v0.x; a0.y += v0.y; a0.z += v0.z; a0.w += v0.w;
        a1.x += v1.x; a1.y += v1.y; a1.z += v1.z; a1.w += v1.w;
        a2.x += v2.x; a2.y += v2.y; a2.z += v2.z; a2.w += v2.w;
        a3.x += v3.x; a3.y += v3.y; a3.z += v3.z; a3.w += v3.w;
    }
    for (; e < hi; ++e) {
        unsigned s0 = grec[e];
        float4 v0 = ((const float4*)src)[s0 * 5 + q];
        a0.x += v0.x; a0.y += v0.y; a0.z += v0.z; a0.w += v0.w;
    }
    a0.x += a1.x + a2.x + a3.x;
    a0.y += a1.y + a2.y + a3.y;
    a0.z += a1.z + a2.z + a3.z;
    a0.w += a1.w + a2.w + a3.w;
    float sc = rsqrtf(fmaxf((float)(hi - lo), 1.0f));
    a0.x *= sc; a0.y *= sc; a0.z *= sc; a0.w *= sc;
    ((float4*)dst)[node * 5 + q] = a0;
}

// FUSED gc1 + encoder-partials, v4: 512 thr (8 waves), 128 nodes/block.
// wave = group(g=wave>>1: 0 gc1 / 1-3 enc octets of packed weights) x nodehalf.
// Packed weights Wp[256][96] -> all groups read the SAME 384B row per k
// (K$-resident); double-buffered 32-k tile with register prefetch; 33.8 KB
// LDS -> 4 blocks/CU = 32 waves = 8 waves/SIMD (R19 was 5.5).
__global__ __launch_bounds__(512) void k_gc1f(const float* __restrict__ nodes,
                                              const float* __restrict__ Wp,
                                              const float* __restrict__ b1,
                                              const float* __restrict__ rs_s,
                                              float* __restrict__ h_pre,
                                              unsigned short* __restrict__ pml) {
    __shared__ float tile[2][128 * 33];    // 33,792 B
    float* gb = &tile[0][0];               // aliased after last buf0 use
    int t = threadIdx.x;
    int wave = __builtin_amdgcn_readfirstlane(t >> 6);  // 0..7
    int lane = t & 63;
    int g  = wave >> 1;       // 0..3: packed-col group g*24..g*24+24
    int nh = wave & 1;        // node half
    int n0 = blockIdx.x * 128;
    int row = nh * 64 + lane;
    int node = n0 + row;

    // stage chunk 0 (k 0..32)
    {
        int idx = t;
#pragma unroll
        for (int r = 0; r < 2; ++r, idx += 512) {
            int rr = idx >> 3, c4 = idx & 7;
            int gn = n0 + rr;
            float4 v = (gn < N_NODES)
                ? ((const float4*)nodes)[(size_t)gn * 64 + c4]
                : make_float4(0.f, 0.f, 0.f, 0.f);
            float* dst = &tile[0][rr * 33 + c4 * 4];
            dst[0] = v.x; dst[1] = v.y; dst[2] = v.z; dst[3] = v.w;
        }
    }
    __syncthreads();

    float acc[24];
#pragma unroll
    for (int j = 0; j < 24; ++j) acc[j] = 0.0f;

    for (int c = 0; c < 8; ++c) {
        float4 p0, p1;
        if (c < 7) {
            int idx = t, rr = idx >> 3, c4 = idx & 7, gn = n0 + rr;
            p0 = (gn < N_NODES)
                ? ((const float4*)nodes)[(size_t)gn * 64 + (c + 1) * 8 + c4]
                : make_float4(0.f, 0.f, 0.f, 0.f);
            idx = t + 512; rr = idx >> 3; c4 = idx & 7; gn = n0 + rr;
            p1 = (gn < N_NODES)
                ? ((const float4*)nodes)[(size_t)gn * 64 + (c + 1) * 8 + c4]
                : make_float4(0.f, 0.f, 0.f, 0.f);
        }
        const float* trow  = &tile[c & 1][row * 33];
        const float* wbase = Wp + (size_t)(c * 32) * 96 + g * 24;
#pragma unroll 4
        for (int kk = 0; kk < 32; ++kk) {
            float x = trow[kk];
            const float* wr = wbase + kk * 96;
#pragma unroll
            for (int j = 0; j < 24; ++j) acc[j] = fmaf(x, wr[j], acc[j]);
        }
        if (c < 7) {
            int idx = t, rr = idx >> 3, c4 = idx & 7;
            float* dst = &tile[(c + 1) & 1][rr * 33 + c4 * 4];
            dst[0] = p0.x; dst[1] = p0.y; dst[2] = p0.z; dst[3] = p0.w;
            idx = t + 512; rr = idx >> 3; c4 = idx & 7;
            dst = &tile[(c + 1) & 1][rr * 33 + c4 * 4];
            dst[0] = p1.x; dst[1] = p1.y; dst[2] = p1.z; dst[3] = p1.w;
        }
        __syncthreads();
    }

    if (node < N_NODES) {
        if (g == 0) {
            // gc1 pre-activations (cols 0..20 of packed; 20..24 are zero-pad)
#pragma unroll
            for (int j = 0; j < GC_HID; ++j) gb[row * 21 + j] = acc[j] + b1[j];
        } else {
            // enc partials: packed cols 24..96 map to pml halfwords 0..64
            // g1 -> pml[0:24), g2 -> pml[24:48), g3 -> pml[48:64) (+8 pad)
            int base = (g - 1) * 24;
            unsigned short* pp = pml + (size_t)node * 64 + base;
            uint4 q0, q1, q2;
            q0.x = (unsigned)f2bf(acc[0]) | ((unsigned)f2bf(acc[1]) << 16);
            q0.y = (unsigned)f2bf(acc[2]) | ((unsigned)f2bf(acc[3]) << 16);
            q0.z = (unsigned)f2bf(acc[4]) | ((unsigned)f2bf(acc[5]) << 16);
            q0.w = (unsigned)f2bf(acc[6]) | ((unsigned)f2bf(acc[7]) << 16);
            q1.x = (unsigned)f2bf(acc[8]) | ((unsigned)f2bf(acc[9]) << 16);
            q1.y = (unsigned)f2bf(acc[10]) | ((unsigned)f2bf(acc[11]) << 16);
            q1.z = (unsigned)f2bf(acc[12]) | ((unsigned)f2bf(acc[13]) << 16);
            q1.w = (unsigned)f2bf(acc[14]) | ((unsigned)f2bf(acc[15]) << 16);
            q2.x = (unsigned)f2bf(acc[16]) | ((unsigned)f2bf(acc[17]) << 16);
            q2.y = (unsigned)f2bf(acc[18]) | ((unsigned)f2bf(acc[19]) << 16);
            q2.z = (unsigned)f2bf(acc[20]) | ((unsigned)f2bf(acc[21]) << 16);
            q2.w = (unsigned)f2bf(acc[22]) | ((unsigned)f2bf(acc[23]) << 16);
            ((uint4*)pp)[0] = q0;
            ((uint4*)pp)[1] = q1;
            if (g != 3) ((uint4*)pp)[2] = q2;
        }
    }
    __syncthreads();
    // softmax finish: threads 0..127, one node each (gb aliased into tile[0])
    if (t < 128) {
        int nn = n0 + t;
        if (nn < N_NODES) {
            float v[GC_HID];
            float mx = -1e30f;
#pragma unroll
            for (int j = 0; j < GC_HID; ++j) {
                v[j] = fmaxf(gb[t * 21 + j], 0.0f);
                mx = fmaxf(mx, v[j]);
            }
            float s = 0.0f;
#pragma unroll
            for (int j = 0; j < GC_HID; ++j) {
                v[j] = __expf(v[j] - mx);
                s += v[j];
            }
            float inv = rs_s[nn] / s;
#pragma unroll
            for (int j = 0; j < GC_HID; ++j) v[j] *= inv;
            float4* o = (float4*)&h_pre[(size_t)nn * GC_HID];
            o[0] = make_float4(v[0],  v[1],  v[2],  v[3]);
            o[1] = make_float4(v[4],  v[5],  v[6],  v[7]);
            o[2] = make_float4(v[8],  v[9],  v[10], v[11]);
            o[3] = make_float4(v[12], v[13], v[14], v[15]);
            o[4] = make_float4(v[16], v[17], v[18], v[19]);
        }
    }
}

// GC layer 2 transform: h2_pre = softmax(relu(h1@W2+b2)) * rs_s
__global__ __launch_bounds__(256) void k_gc2(const float* __restrict__ h1in,
                                             const float* __restrict__ W2,
                                             const float* __restrict__ b2,
                                             const float* __restrict__ rs_s,
                                             float* __restrict__ h2_pre) {
    __shared__ float Wsh[GC_HID * GC_HID];
    __shared__ float bsh[GC_HID];
    int tid = threadIdx.x;
    if (tid < GC_HID * GC_HID) Wsh[tid] = W2[tid];
    if (tid < GC_HID) bsh[tid] = b2[tid];
    __syncthreads();
    int node = blockIdx.x * 256 + tid;
    if (node >= N_NODES) return;
    const float4* ap = (const float4*)&h1in[node * GC_HID];
    float4 a0 = ap[0], a1 = ap[1], a2 = ap[2], a3 = ap[3], a4 = ap[4];
    float h1[GC_HID] = {a0.x,a0.y,a0.z,a0.w, a1.x,a1.y,a1.z,a1.w,
                        a2.x,a2.y,a2.z,a2.w, a3.x,a3.y,a3.z,a3.w,
                        a4.x,a4.y,a4.z,a4.w};
    float t[GC_HID];
#pragma unroll
    for (int j = 0; j < GC_HID; ++j) t[j] = bsh[j];
#pragma unroll
    for (int i = 0; i < GC_HID; ++i) {
        float x = h1[i];
#pragma unroll
        for (int j = 0; j < GC_HID; ++j) t[j] = fmaf(x, Wsh[i * GC_HID + j], t[j]);
    }
    float mx = -1e30f;
#pragma unroll
    for (int j = 0; j < GC_HID; ++j) { t[j] = fmaxf(t[j], 0.0f); mx = fmaxf(mx, t[j]); }
    float s = 0.0f;
#pragma unroll
    for (int j = 0; j < GC_HID; ++j) { t[j] = __expf(t[j] - mx); s += t[j]; }
    float inv = rs_s[node] / s;
#pragma unroll
    for (int j = 0; j < GC_HID; ++j) t[j] *= inv;
    float4* o = (float4*)&h2_pre[node * GC_HID];
    o[0] = make_float4(t[0],  t[1],  t[2],  t[3]);
    o[1] = make_float4(t[4],  t[5],  t[6],  t[7]);
    o[2] = make_float4(t[8],  t[9],  t[10], t[11]);
    o[3] = make_float4(t[12], t[13], t[14], t[15]);
    o[4] = make_float4(t[16], t[17], t[18], t[19]);
}

// encoder finish: mu/ls = bias + pml + h2 @ W[0:20]. Octet split,
// grid (1563, 2), block 256 = 4 waves x 64 nodes.
__global__ __launch_bounds__(256) void k_enc2(const float* __restrict__ h2in,
                                              const unsigned short* __restrict__ pml,
                                              const float* __restrict__ Wmu,
                                              const float* __restrict__ bmu,
                                              const float* __restrict__ Wls,
                                              const float* __restrict__ bls,
                                              float* __restrict__ mu_out,
                                              float* __restrict__ ls_out) {
    int t = threadIdx.x;
    int wave = t >> 6, lane = t & 63;
    int og = __builtin_amdgcn_readfirstlane(wave | ((int)blockIdx.y << 2)); // 0..7
    int half = og >> 2;
    int co = (og & 3) << 3;
    int node = blockIdx.x * 64 + lane;
    if (node >= N_NODES) return;
    const float* W  = half ? Wls : Wmu;
    const float* bb = half ? bls : bmu;
    float* out      = half ? ls_out : mu_out;

    uint4 p = *(const uint4*)(pml + (size_t)node * 64 + half * 32 + co);
    float acc[8];
    acc[0] = bf2f((unsigned short)(p.x & 0xFFFFu));
    acc[1] = bf2f((unsigned short)(p.x >> 16));
    acc[2] = bf2f((unsigned short)(p.y & 0xFFFFu));
    acc[3] = bf2f((unsigned short)(p.y >> 16));
    acc[4] = bf2f((unsigned short)(p.z & 0xFFFFu));
    acc[5] = bf2f((unsigned short)(p.z >> 16));
    acc[6] = bf2f((unsigned short)(p.w & 0xFFFFu));
    acc[7] = bf2f((unsigned short)(p.w >> 16));
#pragma unroll
    for (int j = 0; j < 8; ++j) acc[j] += bb[co + j];

    const float4* hp = (const float4*)(h2in + (size_t)node * GC_HID);
#pragma unroll
    for (int v = 0; v < 5; ++v) {
        float4 hh = hp[v];
#pragma unroll
        for (int c = 0; c < 4; ++c) {
            float x = (c == 0) ? hh.x : (c == 1) ? hh.y : (c == 2) ? hh.z : hh.w;
            const float* wr = W + (v * 4 + c) * Z_DIM + co;
#pragma unroll
            for (int j = 0; j < 8; ++j) acc[j] = fmaf(x, wr[j], acc[j]);
        }
    }
    float4* op = (float4*)(out + (size_t)node * Z_DIM + co);
    op[0] = make_float4(acc[0], acc[1], acc[2], acc[3]);
    op[1] = make_float4(acc[4], acc[5], acc[6], acc[7]);
}

// reparameterization: z = mu + (1e-4 + exp(0.5*ls)) * eps
__global__ __launch_bounds__(256) void k_z(const float* __restrict__ mu,
                                           const float* __restrict__ ls,
                                           const float* __restrict__ eps,
                                           float* __restrict__ z) {
    int i = blockIdx.x * 256 + threadIdx.x;
    if (i >= N_NODES * Z_DIM / 4) return;
    float4 m = ((const float4*)mu)[i];
    float4 l = ((const float4*)ls)[i];
    float4 e = ((const float4*)eps)[i];
    float4 zz;
    zz.x = m.x + (1e-4f + __expf(0.5f * l.x)) * e.x;
    zz.y = m.y + (1e-4f + __expf(0.5f * l.y)) * e.y;
    zz.z = m.z + (1e-4f + __expf(0.5f * l.z)) * e.z;
    zz.w = m.w + (1e-4f + __expf(0.5f * l.w)) * e.w;
    ((float4*)z)[i] = zz;
}

// decoder stage 1: d = relu(z@Wd1+bd1), thread per node (weights uniform)
__global__ __launch_bounds__(256) void k_decd(const float* __restrict__ z,
                                              const float* __restrict__ Wd1,
                                              const float* __restrict__ bd1,
                                              float* __restrict__ dbuf) {
    int node = blockIdx.x * 256 + threadIdx.x;
    if (node >= N_NODES) return;
    float d[DEC_HID];
#pragma unroll
    for (int j = 0; j < DEC_HID; ++j) d[j] = bd1[j];
    const float4* zp = (const float4*)(z + (size_t)node * Z_DIM);
#pragma unroll
    for (int v = 0; v < Z_DIM / 4; ++v) {
        float4 zz = zp[v];
#pragma unroll
        for (int c = 0; c < 4; ++c) {
            float x = (c == 0) ? zz.x : (c == 1) ? zz.y : (c == 2) ? zz.z : zz.w;
            const float* wr = Wd1 + (v * 4 + c) * DEC_HID;
#pragma unroll
            for (int j = 0; j < DEC_HID; ++j) d[j] = fmaf(x, wr[j], d[j]);
        }
    }
    float4* op = (float4*)(dbuf + (size_t)node * DEC_HID);
#pragma unroll
    for (int v = 0; v < DEC_HID / 4; ++v)
        op[v] = make_float4(fmaxf(d[4*v], 0.f), fmaxf(d[4*v+1], 0.f),
                            fmaxf(d[4*v+2], 0.f), fmaxf(d[4*v+3], 0.f));
}

// decoder stage 2: chunk id forced wave-uniform via readfirstlane; lane = node.
__global__ __launch_bounds__(256) void k_decx(const float* __restrict__ dbuf,
                                              const float* __restrict__ Wd2,
                                              const float* __restrict__ bd2,
                                              float* __restrict__ X) {
    int lane = threadIdx.x & 63;
    int wv   = threadIdx.x >> 6;             // 0..3
    int ch   = __builtin_amdgcn_readfirstlane(((blockIdx.x & 1) << 2) | wv);
    int node = (blockIdx.x >> 1) * 64 + lane;
    if (node >= N_NODES) return;
    int co = ch << 5;
    float o[32];
#pragma unroll
    for (int j = 0; j < 32; ++j) o[j] = bd2[co + j];
    const float4* dp = (const float4*)(dbuf + (size_t)node * DEC_HID);
#pragma unroll
    for (int v = 0; v < DEC_HID / 4; ++v) {
        float4 dd = dp[v];
#pragma unroll
        for (int c = 0; c < 4; ++c) {
            float x = (c == 0) ? dd.x : (c == 1) ? dd.y : (c == 2) ? dd.z : dd.w;
            const float* wr = Wd2 + (v * 4 + c) * D_FEAT + co;
#pragma unroll
            for (int j = 0; j < 32; ++j) o[j] = fmaf(x, wr[j], o[j]);
        }
    }
    float4* xp = (float4*)(X + (size_t)node * D_FEAT + co);
#pragma unroll
    for (int v = 0; v < 8; ++v)
        xp[v] = make_float4(o[4*v], o[4*v+1], o[4*v+2], o[4*v+3]);
}

extern "C" void kernel_launch(void* const* d_in, const int* in_sizes, int n_in,
                              void* d_out, int out_size, void* d_ws, size_t ws_size,
                              hipStream_t stream) {
    const float* nodes = (const float*)d_in[0];
    const int*   snd   = (const int*)d_in[1];
    const int*   rcv   = (const int*)d_in[2];
    const float* eps   = (const float*)d_in[3];
    const float* W1    = (const float*)d_in[4];
    const float* b1    = (const float*)d_in[5];
    const float* W2    = (const float*)d_in[6];
    const float* b2    = (const float*)d_in[7];
    const float* Wmu   = (const float*)d_in[8];
    const float* bmu   = (const float*)d_in[9];
    const float* Wls   = (const float*)d_in[10];
    const float* bls   = (const float*)d_in[11];
    const float* Wd1   = (const float*)d_in[12];
    const float* bd1   = (const float*)d_in[13];
    const float* Wd2   = (const float*)d_in[14];
    const float* bd2   = (const float*)d_in[15];

    char* ws = (char*)d_ws;
    float*          h_pre    = (float*)(ws);
    float*          agg      = (float*)(ws + 8000000);
    float*          dbuf     = (float*)(ws);              // overlays h_pre+agg (dead)
    unsigned*       grec     = (unsigned*)(ws + 16000000);
    unsigned*       rec_r    = (unsigned*)(ws + 28804096);
    unsigned short* pml      = (unsigned short*)(ws + 28804096); // overlays rec_r post-gscat
    unsigned short* srow_r   = (unsigned short*)(ws + 41608192);
    unsigned*       pref_t   = (unsigned*)(ws + 42836720);
    float*          zbuf     = (float*)(ws + 41608192);   // overlays srow_r/pref_t/row_ptr post-gather
    unsigned*       row_ptr  = (unsigned*)(ws + 45287504);
    unsigned*       gtot     = (unsigned*)(ws + 45687508);
    unsigned*       gbase    = (unsigned*)(ws + 45689076);
    float*          rs_s     = (float*)(ws + 45690648);
    unsigned char*  rec_s    = (unsigned char*)(ws + 46090648);
    unsigned short* srow_s   = (unsigned short*)(ws + 49291672);
    float*          Wpack    = (float*)(ws + 50520192);

    float* X      = (float*)d_out;
    float* mu_out = X + (size_t)N_NODES * D_FEAT;
    float* ls_out = mu_out + (size_t)N_NODES * Z_DIM;

    k_wpack<<<256, 96, 0, stream>>>(W1, Wmu, Wls, Wpack);
    k_sort<<<NBLK, 512, 0, stream>>>(snd, rcv, rec_r, rec_s, srow_r, srow_s);
    k_degs<<<SB, 512, 0, stream>>>(rec_s, srow_s, rs_s);
    k_scanB<<<SB, 256, 0, stream>>>(srow_r, pref_t, gtot);
    k_scanG<<<1, 512, 0, stream>>>(gtot, gbase);
    k_gscat<<<NBLK, 256, 0, stream>>>(rec_r, srow_r, pref_t, gbase, grec);
    k_sort2<<<SB, 256, 0, stream>>>(grec, gbase, row_ptr);

    // fused gc1 + encoder nodes-partials (nodes read once, packed weights,
    // double-buffered staging, 8 waves/SIMD)
    k_gc1f<<<782, 512, 0, stream>>>(nodes, Wpack, b1, rs_s, h_pre, pml);
    k_gather<<<1563, 320, 0, stream>>>(row_ptr, grec, h_pre, agg);
    k_gc2<<<391, 256, 0, stream>>>(agg, W2, b2, rs_s, h_pre);
    k_gather<<<1563, 320, 0, stream>>>(row_ptr, grec, h_pre, agg);

    k_enc2<<<dim3(1563, 2), 256, 0, stream>>>(agg, pml, Wmu, bmu, Wls, bls,
                                              mu_out, ls_out);
    k_z<<<3125, 256, 0, stream>>>(mu_out, ls_out, eps, zbuf);
    k_decd<<<391, 256, 0, stream>>>(zbuf, Wd1, bd1, dbuf);
    k_decx<<<3126, 256, 0, stream>>>(dbuf, Wd2, bd2, X);
}